// Round 1
// baseline (4294.205 us; speedup 1.0000x reference)
//
#include <hip/hip_runtime.h>
#include <math.h>

#define BN_SC 0.9999950000375f
#define P2N   (6.283185307179586f / 126.f)
#define ATT_SCALE 0.35355339059327373f

enum { M_LOCAL = 0, M_GABOR = 1, M_BNRELU6 = 2, M_BIASRELU = 3 };

// ---------------- weight prep: fold BN scale into w_l1 / w_l2 ----------------
__global__ __launch_bounds__(256) void prep_k(
    const float* __restrict__ w_l1, const float* __restrict__ g_l1, const float* __restrict__ b_l1,
    const float* __restrict__ w_l2, const float* __restrict__ g_l2, const float* __restrict__ b_l2,
    float* __restrict__ w1s, float* __restrict__ w2s, float* __restrict__ bs)
{
  int i = blockIdx.x * 256 + threadIdx.x;
  if (i < 36864) w1s[i] = w_l1[i] * (g_l1[i / 576] * BN_SC);
  if (i < 4096)  w2s[i] = w_l2[i] * (g_l2[i / 64] * BN_SC);
  if (i < 64)    bs[i]  = b_l1[i] + b_l2[i];
}

// ---------------- generic 3x3 conv, 64->64 ch, LDS tiled ----------------
// block: 256 thr = 16x16 pixels; blockIdx.x = tile, .y = batch, .z = 16-ch out group
// MODE 0: out = conv3x3(w_a_prescaled) + center*w_b_prescaled + pa[c]         (local_pre)
// MODE 1: out = conv3x3(c<32 ? wa : wb) + (c<32 ? pa[c] : pb[c-32])           (gabor, pad0)
// MODE 2: out = clamp(conv3x3(wa)*(pa[c]*BN_SC)+pb[c], 0, 6)                  (w_post)
// MODE 3: out = relu(conv3x3(wa) + pa[c])                                     (w_gc1)
template<int MODE, int IN_HW, int OUT_HW, int PAD>
__global__ __launch_bounds__(256)
void conv3x3_k(const float* __restrict__ in, const float* __restrict__ wa,
               const float* __restrict__ wb, const float* __restrict__ pa,
               const float* __restrict__ pb, float* __restrict__ out)
{
  __shared__ float tile[16 * 324]; // 16 cin x 18x18
  const int tid = threadIdx.x;
  const int tx = tid & 15, ty = tid >> 4;
  const int nt = (OUT_HW + 15) >> 4;
  const int bx = blockIdx.x % nt, by = blockIdx.x / nt;
  const int b = blockIdx.y, cg = blockIdx.z;
  const int ox0 = bx * 16, oy0 = by * 16;
  float acc[16];
#pragma unroll
  for (int i = 0; i < 16; ++i) acc[i] = 0.f;

  for (int cc = 0; cc < 64; cc += 16) {
    __syncthreads();
#pragma unroll
    for (int k = 0; k < 21; ++k) {
      int e = tid + k * 256;
      if (e < 16 * 324) {
        int ci = e / 324, r = e % 324;
        int yy = r / 18, xx = r % 18;
        int iy = oy0 + yy - PAD, ix = ox0 + xx - PAD;
        float v = 0.f;
        if (iy >= 0 && iy < IN_HW && ix >= 0 && ix < IN_HW)
          v = in[((size_t)(b * 64 + cc + ci) * IN_HW + iy) * IN_HW + ix];
        tile[ci * 324 + r] = v;
      }
    }
    __syncthreads();
    for (int ci = 0; ci < 16; ++ci) {
      float v[9];
#pragma unroll
      for (int dy = 0; dy < 3; ++dy)
#pragma unroll
        for (int dx = 0; dx < 3; ++dx)
          v[dy * 3 + dx] = tile[ci * 324 + (ty + dy) * 18 + (tx + dx)];
      const int cin = cc + ci;
#pragma unroll
      for (int co = 0; co < 16; ++co) {
        const int c = cg * 16 + co;
        const float* wk;
        if (MODE == M_GABOR)
          wk = (c < 32) ? (wa + ((size_t)c * 64 + cin) * 9)
                        : (wb + ((size_t)(c - 32) * 64 + cin) * 9);
        else
          wk = wa + ((size_t)c * 64 + cin) * 9;
        float s = v[0]*wk[0] + v[1]*wk[1] + v[2]*wk[2]
                + v[3]*wk[3] + v[4]*wk[4] + v[5]*wk[5]
                + v[6]*wk[6] + v[7]*wk[7] + v[8]*wk[8];
        if (MODE == M_LOCAL) s += v[4] * wb[(size_t)c * 64 + cin];
        acc[co] += s;
      }
    }
  }
  const int oy = oy0 + ty, ox = ox0 + tx;
  if (oy < OUT_HW && ox < OUT_HW) {
#pragma unroll
    for (int co = 0; co < 16; ++co) {
      const int c = cg * 16 + co;
      float r = acc[co];
      if (MODE == M_LOCAL)        r += pa[c];
      else if (MODE == M_GABOR)   r += (c < 32) ? pa[c] : pb[c - 32];
      else if (MODE == M_BNRELU6) { r = r * (pa[c] * BN_SC) + pb[c]; r = fminf(fmaxf(r, 0.f), 6.f); }
      else                        r = fmaxf(r + pa[c], 0.f);
      out[((size_t)(b * 64 + c) * OUT_HW + oy) * OUT_HW + ox] = r;
    }
  }
}

// ---------------- DFT stage 1: rows, real->complex, forward ----------------
__global__ __launch_bounds__(128)
void dft_rows_fwd_k(const float* __restrict__ in, float* __restrict__ outC, int planeBase)
{
  const int bi = blockIdx.x;
  const int lp = bi / 126, n1 = bi % 126;
  const float* row = in + (size_t)(planeBase + lp) * 15876 + (size_t)n1 * 126;
  __shared__ float r[126];
  if (threadIdx.x < 126) r[threadIdx.x] = row[threadIdx.x];
  __syncthreads();
  const int k2 = threadIdx.x;
  if (k2 < 126) {
    float astp = -P2N * (float)k2;
    float ct = cosf(astp), st = sinf(astp);
    float ar = 0.f, ai = 0.f;
    for (int blk = 0; blk < 6; ++blk) {
      int m = (k2 * (blk * 21)) % 126;
      float ang = -P2N * (float)m;
      float c = cosf(ang), s = sinf(ang);
#pragma unroll
      for (int u = 0; u < 21; ++u) {
        float v = r[blk * 21 + u];
        ar += v * c; ai += v * s;
        float cn = c * ct - s * st; s = c * st + s * ct; c = cn;
      }
    }
    float* o = outC + ((size_t)lp * 15876 + (size_t)n1 * 126 + k2) * 2;
    o[0] = ar; o[1] = ai;
  }
}

// ------- DFT stage 2: cols forward + fused highpass mask * |F| * (1/N^2) -------
__global__ __launch_bounds__(256)
void dft_cols_fwd_mask_k(const float* __restrict__ inC, float* __restrict__ outC)
{
  __shared__ float S[126 * 32 * 2];
  const int lp = blockIdx.x >> 2, g = blockIdx.x & 3;
  const int gbase = g * 32;
  for (int e = threadIdx.x; e < 126 * 32; e += 256) {
    int n1 = e >> 5, c = e & 31;
    int k2 = gbase + c;
    float re = 0.f, im = 0.f;
    if (k2 < 126) {
      const float* p = inC + ((size_t)lp * 15876 + (size_t)n1 * 126 + k2) * 2;
      re = p[0]; im = p[1];
    }
    S[e * 2] = re; S[e * 2 + 1] = im;
  }
  __syncthreads();
  for (int e = threadIdx.x; e < 126 * 32; e += 256) {
    int k1 = e >> 5, c = e & 31;
    int k2 = gbase + c;
    if (k2 >= 126) continue;
    float astp = -P2N * (float)k1;
    float ct = cosf(astp), st = sinf(astp);
    float ar = 0.f, ai = 0.f;
    for (int blk = 0; blk < 6; ++blk) {
      int m = (k1 * (blk * 21)) % 126;
      float ang = -P2N * (float)m;
      float cr = cosf(ang), sr = sinf(ang);
#pragma unroll
      for (int u = 0; u < 21; ++u) {
        int n1 = blk * 21 + u;
        float xr = S[(n1 * 32 + c) * 2], xi = S[(n1 * 32 + c) * 2 + 1];
        ar += xr * cr - xi * sr;
        ai += xr * sr + xi * cr;
        float cn = cr * ct - sr * st; sr = cr * st + sr * ct; cr = cn;
      }
    }
    int f1 = (k1 <= 62) ? k1 : k1 - 126;
    int f2 = (k2 <= 62) ? k2 : k2 - 126;
    float mag = sqrtf(ar * ar + ai * ai);
    float sc = (f1 * f1 + f2 * f2 > 1600) ? (mag * (1.f / 15876.f)) : 0.f;
    float* o = outC + ((size_t)lp * 15876 + (size_t)k1 * 126 + k2) * 2;
    o[0] = ar * sc; o[1] = ai * sc;
  }
}

// ---------------- DFT stage 3: cols inverse, complex->complex ----------------
__global__ __launch_bounds__(256)
void dft_cols_inv_k(const float* __restrict__ inC, float* __restrict__ outC)
{
  __shared__ float S[126 * 32 * 2];
  const int lp = blockIdx.x >> 2, g = blockIdx.x & 3;
  const int gbase = g * 32;
  for (int e = threadIdx.x; e < 126 * 32; e += 256) {
    int k1 = e >> 5, c = e & 31;
    int k2 = gbase + c;
    float re = 0.f, im = 0.f;
    if (k2 < 126) {
      const float* p = inC + ((size_t)lp * 15876 + (size_t)k1 * 126 + k2) * 2;
      re = p[0]; im = p[1];
    }
    S[e * 2] = re; S[e * 2 + 1] = im;
  }
  __syncthreads();
  for (int e = threadIdx.x; e < 126 * 32; e += 256) {
    int n1 = e >> 5, c = e & 31;
    int k2 = gbase + c;
    if (k2 >= 126) continue;
    float astp = P2N * (float)n1;
    float ct = cosf(astp), st = sinf(astp);
    float ar = 0.f, ai = 0.f;
    for (int blk = 0; blk < 6; ++blk) {
      int m = (n1 * (blk * 21)) % 126;
      float ang = P2N * (float)m;
      float cr = cosf(ang), sr = sinf(ang);
#pragma unroll
      for (int u = 0; u < 21; ++u) {
        int k1 = blk * 21 + u;
        float xr = S[(k1 * 32 + c) * 2], xi = S[(k1 * 32 + c) * 2 + 1];
        ar += xr * cr - xi * sr;
        ai += xr * sr + xi * cr;
        float cn = cr * ct - sr * st; sr = cr * st + sr * ct; cr = cn;
      }
    }
    float* o = outC + ((size_t)lp * 15876 + (size_t)n1 * 126 + k2) * 2;
    o[0] = ar; o[1] = ai;
  }
}

// ------- DFT stage 4: rows inverse -> real, abs, mix with xc0 via fw -------
__global__ __launch_bounds__(128)
void dft_rows_inv_mix_k(const float* __restrict__ inC, const float* __restrict__ xc0,
                        const float* __restrict__ gb_w, float* __restrict__ out, int planeBase)
{
  const int bi = blockIdx.x;
  const int lp = bi / 126, n1 = bi % 126;
  __shared__ float Zr[126], Zi[126];
  if (threadIdx.x < 126) {
    const float* p = inC + ((size_t)lp * 15876 + (size_t)n1 * 126 + threadIdx.x) * 2;
    Zr[threadIdx.x] = p[0]; Zi[threadIdx.x] = p[1];
  }
  __syncthreads();
  const int n2 = threadIdx.x;
  if (n2 < 126) {
    float astp = P2N * (float)n2;
    float ct = cosf(astp), st = sinf(astp);
    float a = 0.f;
    for (int blk = 0; blk < 6; ++blk) {
      int m = (n2 * (blk * 21)) % 126;
      float ang = P2N * (float)m;
      float c = cosf(ang), s = sinf(ang);
#pragma unroll
      for (int u = 0; u < 21; ++u) {
        int k2 = blk * 21 + u;
        a += Zr[k2] * c - Zi[k2] * s;
        float cn = c * ct - s * st; s = c * st + s * ct; c = cn;
      }
    }
    float w0 = fmaxf(gb_w[0], 0.f), w1 = fmaxf(gb_w[1], 0.f);
    float inv = 1.f / (w0 + w1 + 1e-8f);
    size_t gi = (size_t)(planeBase + lp) * 15876 + (size_t)n1 * 126 + n2;
    out[gi] = (w0 * inv) * fabsf(a) + (w1 * inv) * xc0[gi];
  }
}

// ---------------- maxpool 2x2 stride1: 126 -> 125 ----------------
__global__ __launch_bounds__(256) void mp1_k(const float* __restrict__ in, float* __restrict__ out)
{
  int idx = blockIdx.x * 256 + threadIdx.x;
  if (idx >= 512 * 125 * 125) return;
  int x = idx % 125, y = (idx / 125) % 125, p = idx / 15625;
  const float* ip = in + (size_t)p * 15876 + (size_t)y * 126 + x;
  out[idx] = fmaxf(fmaxf(ip[0], ip[1]), fmaxf(ip[126], ip[127]));
}

// ---------------- conv3x3 stride2, valid: 125 -> 62, + bias + relu ----------------
__global__ __launch_bounds__(256)
void convgc_k(const float* __restrict__ in, const float* __restrict__ w,
              const float* __restrict__ bias, float* __restrict__ out)
{
  int idx = blockIdx.x * 256 + threadIdx.x;
  if (idx >= 8 * 64 * 62 * 62) return;
  int x = idx % 62, y = (idx / 62) % 62;
  int co = (idx / 3844) % 64, b = idx / 246016;
  float s = bias[co];
  for (int cin = 0; cin < 64; ++cin) {
    const float* ip = in + ((size_t)(b * 64 + cin) * 125 + 2 * y) * 125 + 2 * x;
    const float* wk = w + ((size_t)co * 64 + cin) * 9;
    s += ip[0]   * wk[0] + ip[1]   * wk[1] + ip[2]   * wk[2]
       + ip[125] * wk[3] + ip[126] * wk[4] + ip[127] * wk[5]
       + ip[250] * wk[6] + ip[251] * wk[7] + ip[252] * wk[8];
  }
  out[idx] = fmaxf(s, 0.f);
}

// ---------------- maxpool 2x2 stride2: 62 -> 31 ----------------
__global__ __launch_bounds__(256) void mp2_k(const float* __restrict__ in, float* __restrict__ out)
{
  int idx = blockIdx.x * 256 + threadIdx.x;
  if (idx >= 512 * 31 * 31) return;
  int x = idx % 31, y = (idx / 31) % 31, p = idx / 961;
  const float* ip = in + (size_t)p * 3844 + (size_t)(2 * y) * 62 + 2 * x;
  out[idx] = fmaxf(fmaxf(ip[0], ip[1]), fmaxf(ip[62], ip[63]));
}

// ---------------- bilinear resize 31 -> 128 (half-pixel, edge-clamped) ----------------
__global__ __launch_bounds__(256) void resize_k(const float* __restrict__ in, float* __restrict__ out)
{
  int idx = blockIdx.x * 256 + threadIdx.x;
  if (idx >= 512 * 128 * 128) return;
  int x = idx & 127, y = (idx >> 7) & 127, p = idx >> 14;
  float sy = (y + 0.5f) * (31.f / 128.f) - 0.5f; sy = fminf(fmaxf(sy, 0.f), 30.f);
  float sx = (x + 0.5f) * (31.f / 128.f) - 0.5f; sx = fminf(fmaxf(sx, 0.f), 30.f);
  int y0 = (int)sy; float fy = sy - (float)y0; int y1 = min(y0 + 1, 30);
  int x0 = (int)sx; float fx = sx - (float)x0; int x1 = min(x0 + 1, 30);
  const float* ip = in + (size_t)p * 961;
  float v = (1.f - fy) * ((1.f - fx) * ip[y0 * 31 + x0] + fx * ip[y0 * 31 + x1])
          + fy         * ((1.f - fx) * ip[y1 * 31 + x0] + fx * ip[y1 * 31 + x1]);
  out[idx] = v;
}

// ---------------- 1x1 conv (w_gc2 + bias) + log_softmax over 64 channels ----------------
__global__ __launch_bounds__(256)
void pwlsm_k(const float* __restrict__ in, const float* __restrict__ w,
             const float* __restrict__ bias, float* __restrict__ out)
{
  __shared__ float zs[64 * 256];
  int idx = blockIdx.x * 256 + threadIdx.x;
  int b = idx >> 14, px = idx & 16383;
  const float* ip = in + ((size_t)b << 20) + px;
  float v[64];
#pragma unroll
  for (int i = 0; i < 64; ++i) v[i] = ip[(size_t)i << 14];
  float m = -1e30f;
  for (int co = 0; co < 64; ++co) {
    float s = bias[co];
    const float* wk = w + co * 64;
#pragma unroll
    for (int i = 0; i < 64; ++i) s += v[i] * wk[i];
    zs[co * 256 + threadIdx.x] = s;
    m = fmaxf(m, s);
  }
  float sum = 0.f;
  for (int co = 0; co < 64; ++co) sum += __expf(zs[co * 256 + threadIdx.x] - m);
  float lse = m + __logf(sum);
  float* op = out + ((size_t)b << 20) + px;
  for (int co = 0; co < 64; ++co) op[(size_t)co << 14] = zs[co * 256 + threadIdx.x] - lse;
}

// ---------------- windowed attention (8x8 win, 8 heads, hd 8), fused qkv ----------------
__global__ __launch_bounds__(256)
void attn_k(const float* __restrict__ x, const float* __restrict__ wqkv,
            const float* __restrict__ rpb, const int* __restrict__ relidx,
            float* __restrict__ o_out)
{
  __shared__ float qkv_s[3 * 8 * 64 * 8]; // [t][h][i][d]
  __shared__ float ds[4096];              // x-tile, then dots
  const int tid = threadIdx.x;
  const int win = blockIdx.x;
  const int b = win >> 8, gy = (win >> 4) & 15, gx = win & 15;
  const int y0 = gy * 8, x0 = gx * 8;

  for (int e = tid; e < 4096; e += 256) {
    int cin = e >> 6, pix = e & 63;
    ds[e] = x[((size_t)(b * 64 + cin) * 128 + (y0 + (pix >> 3))) * 128 + x0 + (pix & 7)];
  }
  __syncthreads();
  for (int e = tid; e < 12288; e += 256) {
    int ch = e >> 6, pix = e & 63;
    const float* wk = wqkv + ch * 64;
    float s = 0.f;
#pragma unroll
    for (int cin = 0; cin < 64; ++cin) s += ds[cin * 64 + pix] * wk[cin];
    int t = ch >> 6, h = (ch >> 3) & 7, d = ch & 7;
    qkv_s[((t * 8 + h) * 64 + pix) * 8 + d] = s;
  }
  __syncthreads();

  for (int h = 0; h < 8; ++h) {
    const float* qh = qkv_s + (0 * 8 + h) * 512;
    const float* kh = qkv_s + (1 * 8 + h) * 512;
    const float* vh = qkv_s + (2 * 8 + h) * 512;
    for (int e = tid; e < 4096; e += 256) {
      int i = e >> 6, j = e & 63;
      float s = 0.f;
#pragma unroll
      for (int d = 0; d < 8; ++d) s += qh[i * 8 + d] * kh[j * 8 + d];
      ds[e] = s * ATT_SCALE + rpb[relidx[e] * 8 + h];
    }
    __syncthreads();
    if (tid < 64) {
      float m = -1e30f;
      for (int j = 0; j < 64; ++j) m = fmaxf(m, ds[tid * 64 + j]);
      float sum = 0.f;
      for (int j = 0; j < 64; ++j) { float p = __expf(ds[tid * 64 + j] - m); ds[tid * 64 + j] = p; sum += p; }
      float inv = 1.f / sum;
      for (int j = 0; j < 64; ++j) ds[tid * 64 + j] *= inv;
    }
    __syncthreads();
    for (int e = tid; e < 512; e += 256) {
      int i = e >> 3, d = e & 7;
      float s = 0.f;
#pragma unroll
      for (int j = 0; j < 64; ++j) s += ds[i * 64 + j] * vh[j * 8 + d];
      qkv_s[(h * 64 + i) * 8 + d] = s; // overwrite q[h] slot with o[h]
    }
    __syncthreads();
  }
  for (int e = tid; e < 4096; e += 256) {
    int c = e >> 6, pix = e & 63;
    int h = c >> 3, d = c & 7;
    o_out[((size_t)(b * 64 + c) * 128 + y0 + (pix >> 3)) * 128 + x0 + (pix & 7)] =
        qkv_s[(h * 64 + pix) * 8 + d];
  }
}

// ------- directional avg pools (reflect+zero pad semantics) + add local -------
__global__ __launch_bounds__(256)
void avgadd_k(const float* __restrict__ o, const float* __restrict__ loc, float* __restrict__ out)
{
  int idx = blockIdx.x * 256 + threadIdx.x;
  if (idx >= 8388608) return;
  int x = idx & 127, y = (idx >> 7) & 127;
  size_t p = (size_t)(idx >> 14);
  const float* op = o + (p << 14);
  float s1 = 0.f, s2 = 0.f;
#pragma unroll
  for (int t = 0; t < 8; ++t) {
    int r = y - 3 + t;
    if (r >= 0 && r <= 128) { int rr = (r == 128) ? 126 : r; s1 += op[rr * 128 + x]; }
    int cc = x - 3 + t;
    if (cc >= 0 && cc <= 128) { int ss = (cc == 128) ? 126 : cc; s2 += op[y * 128 + ss]; }
  }
  out[idx] = 0.125f * (s1 + s2) + loc[idx];
}

// ---------------- depthwise 8x8 conv (pad_out + pad3, zero) + BN ----------------
__global__ __launch_bounds__(256)
void dw_k(const float* __restrict__ in, const float* __restrict__ w,
          const float* __restrict__ g, const float* __restrict__ bb, float* __restrict__ out)
{
  __shared__ float t[23 * 23];
  const int tid = threadIdx.x;
  const int tx = tid & 15, ty = tid >> 4;
  const int x0 = blockIdx.x * 16, y0 = blockIdx.y * 16;
  const int pc = blockIdx.z;
  const int c = pc & 63;
  const float* ip = in + (size_t)pc * 16384;
  for (int e = tid; e < 529; e += 256) {
    int yy = e / 23, xx = e % 23;
    int iy = y0 + yy - 3, ix = x0 + xx - 3;
    t[e] = (iy >= 0 && iy < 128 && ix >= 0 && ix < 128) ? ip[iy * 128 + ix] : 0.f;
  }
  __syncthreads();
  const float* wk = w + c * 64;
  float s = 0.f;
#pragma unroll
  for (int ky = 0; ky < 8; ++ky)
#pragma unroll
    for (int kx = 0; kx < 8; ++kx)
      s += t[(ty + ky) * 23 + tx + kx] * wk[ky * 8 + kx];
  out[(size_t)pc * 16384 + (y0 + ty) * 128 + x0 + tx] = s * (g[c] * BN_SC) + bb[c];
}

// ---------------- final 1x1 conv (w_pw, no bias) ----------------
__global__ __launch_bounds__(256)
void pw_k(const float* __restrict__ in, const float* __restrict__ w, float* __restrict__ out)
{
  int idx = blockIdx.x * 256 + threadIdx.x;
  int b = idx >> 14, px = idx & 16383;
  const float* ip = in + ((size_t)b << 20) + px;
  float v[64];
#pragma unroll
  for (int i = 0; i < 64; ++i) v[i] = ip[(size_t)i << 14];
  float* op = out + ((size_t)b << 20) + px;
  for (int co = 0; co < 64; ++co) {
    const float* wk = w + co * 64;
    float s = 0.f;
#pragma unroll
    for (int i = 0; i < 64; ++i) s += v[i] * wk[i];
    op[(size_t)co << 14] = s;
  }
}

// =======================================================================
extern "C" void kernel_launch(void* const* d_in, const int* in_sizes, int n_in,
                              void* d_out, int out_size, void* d_ws, size_t ws_size,
                              hipStream_t stream)
{
  const float* x      = (const float*)d_in[0];
  const float* w_qkv  = (const float*)d_in[1];
  const float* w_l1   = (const float*)d_in[2];
  const float* g_l1   = (const float*)d_in[3];
  const float* b_l1   = (const float*)d_in[4];
  const float* w_l2   = (const float*)d_in[5];
  const float* g_l2   = (const float*)d_in[6];
  const float* b_l2   = (const float*)d_in[7];
  const float* f_cos  = (const float*)d_in[8];
  const float* f_sin  = (const float*)d_in[9];
  const float* gb_b1  = (const float*)d_in[10];
  const float* gb_b2  = (const float*)d_in[11];
  const float* gb_w   = (const float*)d_in[12];
  const float* w_post = (const float*)d_in[13];
  const float* g_post = (const float*)d_in[14];
  const float* b_post = (const float*)d_in[15];
  const float* w_gc   = (const float*)d_in[16];
  const float* b_gc   = (const float*)d_in[17];
  const float* w_gc1  = (const float*)d_in[18];
  const float* b_gc1  = (const float*)d_in[19];
  const float* w_gc2  = (const float*)d_in[20];
  const float* b_gc2  = (const float*)d_in[21];
  const float* rpb    = (const float*)d_in[22];
  const float* w_dw   = (const float*)d_in[23];
  const float* g_proj = (const float*)d_in[24];
  const float* b_proj = (const float*)d_in[25];
  const float* w_pw   = (const float*)d_in[26];
  const int*   relidx = (const int*)d_in[27];
  float* out = (float*)d_out;

  char* ws = (char*)d_ws;
  float* R1  = (float*)(ws + 0);           // 33.5 MB: local_pre / xc1 / xc3 / xc6 / local / dwout
  float* R2  = (float*)(ws + 33554432);    // 33.5 MB: xc0 / xc2 / xc7 / o / dwout
  float* R3  = (float*)(ws + 67108864);    // 65 MB:   FFT C1|C2 / xc4 / xc5 / out0 / prep-weights
  float* C1  = R3;
  float* C2  = (float*)(ws + 67108864 + 32514048);
  float* XC5 = (float*)(ws + 67108864 + 16777216);
  float* W1S = (float*)(ws + 67108864);            // prep (dead before FFT uses R3)
  float* W2S = (float*)(ws + 67108864 + 147456);
  float* BLS = (float*)(ws + 67108864 + 163840);

  // 1. fold BN into local-branch weights
  prep_k<<<144, 256, 0, stream>>>(w_l1, g_l1, b_l1, w_l2, g_l2, b_l2, W1S, W2S, BLS);
  // 2. local_pre = bn(conv1x1) + bn(conv3x3)  -> R1
  conv3x3_k<M_LOCAL, 128, 128, 1><<<dim3(64, 8, 4), 256, 0, stream>>>(x, W1S, W2S, BLS, nullptr, R1);
  // 3. gabor conv (valid, cos||sin + biases)  -> R2 (xc0, 126x126)
  conv3x3_k<M_GABOR, 128, 126, 0><<<dim3(64, 8, 4), 256, 0, stream>>>(R1, f_cos, f_sin, gb_b1, gb_b2, R2);
  // 4. fft_h + fw-mix, 2 chunks of 256 planes -> R1 (xc1)
  for (int chunk = 0; chunk < 2; ++chunk) {
    int pb = chunk * 256;
    dft_rows_fwd_k<<<256 * 126, 128, 0, stream>>>(R2, C1, pb);
    dft_cols_fwd_mask_k<<<256 * 4, 256, 0, stream>>>(C1, C2);
    dft_cols_inv_k<<<256 * 4, 256, 0, stream>>>(C2, C1);
    dft_rows_inv_mix_k<<<256 * 126, 128, 0, stream>>>(C1, R2, gb_w, R1, pb);
  }
  // 5. relu6(bn(conv3x3 w_post)) -> R2 (xc2)
  conv3x3_k<M_BNRELU6, 126, 126, 1><<<dim3(64, 8, 4), 256, 0, stream>>>(R1, w_post, nullptr, g_post, b_post, R2);
  // 6. maxpool 2x2 s1 -> R1 (125^2)
  mp1_k<<<31250, 256, 0, stream>>>(R2, R1);
  // 7. relu(conv3x3 s2 w_gc) -> R3 (62^2)
  convgc_k<<<7688, 256, 0, stream>>>(R1, w_gc, b_gc, R3);
  // 8. maxpool 2x2 s2 -> XC5 (31^2)
  mp2_k<<<1922, 256, 0, stream>>>(R3, XC5);
  // 9. bilinear resize 31 -> 128 -> R1 (xc6)
  resize_k<<<32768, 256, 0, stream>>>(XC5, R1);
  // 10. relu(conv3x3 w_gc1 + b) -> R2 (xc7)
  conv3x3_k<M_BIASRELU, 128, 128, 1><<<dim3(64, 8, 4), 256, 0, stream>>>(R1, w_gc1, nullptr, b_gc1, nullptr, R2);
  // 11. 1x1 conv w_gc2 + log_softmax -> R1 (local)
  pwlsm_k<<<512, 256, 0, stream>>>(R2, w_gc2, b_gc2, R1);
  // 12. window attention -> R2 (o)
  attn_k<<<2048, 256, 0, stream>>>(x, w_qkv, rpb, relidx, R2);
  // 13. ox + oy + local -> R3 (out0)
  avgadd_k<<<32768, 256, 0, stream>>>(R2, R1, R3);
  // 14. depthwise 8x8 + bn -> R2
  dw_k<<<dim3(8, 8, 512), 256, 0, stream>>>(R3, w_dw, g_proj, b_proj, R2);
  // 15. 1x1 conv w_pw -> d_out
  pw_k<<<512, 256, 0, stream>>>(R2, w_pw, out);
  (void)in_sizes; (void)n_in; (void)out_size; (void)ws_size;
}

// Round 2
// 2920.146 us; speedup vs baseline: 1.4705x; 1.4705x over previous
//
#include <hip/hip_runtime.h>
#include <math.h>

#define BN_SC 0.9999950000375f
#define P2N   (6.283185307179586f / 126.f)
#define ATT_SCALE 0.35355339059327373f

enum { M_LOCAL = 0, M_GABOR = 1, M_BNRELU6 = 2, M_BIASRELU = 3 };

// ---------------- weight prep: fold BN scale into w_l1 / w_l2 ----------------
__global__ __launch_bounds__(256) void prep_k(
    const float* __restrict__ w_l1, const float* __restrict__ g_l1, const float* __restrict__ b_l1,
    const float* __restrict__ w_l2, const float* __restrict__ g_l2, const float* __restrict__ b_l2,
    float* __restrict__ w1s, float* __restrict__ w2s, float* __restrict__ bs)
{
  int i = blockIdx.x * 256 + threadIdx.x;
  if (i < 36864) w1s[i] = w_l1[i] * (g_l1[i / 576] * BN_SC);
  if (i < 4096)  w2s[i] = w_l2[i] * (g_l2[i / 64] * BN_SC);
  if (i < 64)    bs[i]  = b_l1[i] + b_l2[i];
}

// ------------- rpb bias pre-gather: rpbt[h][j*64+i] = rpb[relidx[i*64+j]*8+h] -------------
__global__ __launch_bounds__(256) void rpbprep_k(
    const float* __restrict__ rpb, const int* __restrict__ relidx, float* __restrict__ rpbt)
{
  int idx = blockIdx.x * 256 + threadIdx.x; // 32768
  int h = idx >> 12, r = idx & 4095, j = r >> 6, i = r & 63;
  rpbt[idx] = rpb[relidx[i * 64 + j] * 8 + h];
}

// ---------------- generic 3x3 conv, 64->64 ch, LDS tiled ----------------
template<int MODE, int IN_HW, int OUT_HW, int PAD>
__global__ __launch_bounds__(256)
void conv3x3_k(const float* __restrict__ in, const float* __restrict__ wa,
               const float* __restrict__ wb, const float* __restrict__ pa,
               const float* __restrict__ pb, float* __restrict__ out)
{
  __shared__ float tile[16 * 324]; // 16 cin x 18x18
  const int tid = threadIdx.x;
  const int tx = tid & 15, ty = tid >> 4;
  const int nt = (OUT_HW + 15) >> 4;
  const int bx = blockIdx.x % nt, by = blockIdx.x / nt;
  const int b = blockIdx.y, cg = blockIdx.z;
  const int ox0 = bx * 16, oy0 = by * 16;
  float acc[16];
#pragma unroll
  for (int i = 0; i < 16; ++i) acc[i] = 0.f;

  for (int cc = 0; cc < 64; cc += 16) {
    __syncthreads();
#pragma unroll
    for (int k = 0; k < 21; ++k) {
      int e = tid + k * 256;
      if (e < 16 * 324) {
        int ci = e / 324, r = e % 324;
        int yy = r / 18, xx = r % 18;
        int iy = oy0 + yy - PAD, ix = ox0 + xx - PAD;
        float v = 0.f;
        if (iy >= 0 && iy < IN_HW && ix >= 0 && ix < IN_HW)
          v = in[((size_t)(b * 64 + cc + ci) * IN_HW + iy) * IN_HW + ix];
        tile[ci * 324 + r] = v;
      }
    }
    __syncthreads();
    for (int ci = 0; ci < 16; ++ci) {
      float v[9];
#pragma unroll
      for (int dy = 0; dy < 3; ++dy)
#pragma unroll
        for (int dx = 0; dx < 3; ++dx)
          v[dy * 3 + dx] = tile[ci * 324 + (ty + dy) * 18 + (tx + dx)];
      const int cin = cc + ci;
#pragma unroll
      for (int co = 0; co < 16; ++co) {
        const int c = cg * 16 + co;
        const float* wk;
        if (MODE == M_GABOR)
          wk = (c < 32) ? (wa + ((size_t)c * 64 + cin) * 9)
                        : (wb + ((size_t)(c - 32) * 64 + cin) * 9);
        else
          wk = wa + ((size_t)c * 64 + cin) * 9;
        float s = v[0]*wk[0] + v[1]*wk[1] + v[2]*wk[2]
                + v[3]*wk[3] + v[4]*wk[4] + v[5]*wk[5]
                + v[6]*wk[6] + v[7]*wk[7] + v[8]*wk[8];
        if (MODE == M_LOCAL) s += v[4] * wb[(size_t)c * 64 + cin];
        acc[co] += s;
      }
    }
  }
  const int oy = oy0 + ty, ox = ox0 + tx;
  if (oy < OUT_HW && ox < OUT_HW) {
#pragma unroll
    for (int co = 0; co < 16; ++co) {
      const int c = cg * 16 + co;
      float r = acc[co];
      if (MODE == M_LOCAL)        r += pa[c];
      else if (MODE == M_GABOR)   r += (c < 32) ? pa[c] : pb[c - 32];
      else if (MODE == M_BNRELU6) { r = r * (pa[c] * BN_SC) + pb[c]; r = fminf(fmaxf(r, 0.f), 6.f); }
      else                        r = fmaxf(r + pa[c], 0.f);
      out[((size_t)(b * 64 + c) * OUT_HW + oy) * OUT_HW + ox] = r;
    }
  }
}

// ======================= DFT (126-pt), table-based, Hermitian-half =======================
// Complex working buffers are compact: per plane [n][k2] with k2 in [0,63], row stride 64
// complex (128 floats), plane stride 16128 floats.

// Stage 1: rows forward, real->complex, radix-2 over n (even/odd samples), k2 in [0,63]
__global__ __launch_bounds__(64)
void dft_rows_fwd_k(const float* __restrict__ in, float* __restrict__ outC, int planeBase)
{
  __shared__ float2 r2[63];
  __shared__ float2 T[126];
  const int lp = blockIdx.x / 126, n1 = blockIdx.x % 126;
  const int tid = threadIdx.x;
  const float2* row = (const float2*)(in + (size_t)(planeBase + lp) * 15876 + (size_t)n1 * 126);
  if (tid < 63) r2[tid] = row[tid];
  for (int e = tid; e < 126; e += 64) { float s, c; sincosf(P2N * (float)e, &s, &c); T[e] = make_float2(c, s); }
  __syncthreads();
  const int k2 = tid;           // 0..63
  const int inc = (2 * k2) % 126;
  int m = 0;
  float Er = 0.f, Ei = 0.f, Or = 0.f, Oi = 0.f;
  for (int n = 0; n < 63; ++n) {
    float2 rv = r2[n];
    float2 t = T[m];
    Er += rv.x * t.x; Ei -= rv.x * t.y;
    Or += rv.y * t.x; Oi -= rv.y * t.y;
    m += inc; if (m >= 126) m -= 126;
  }
  float c = T[k2].x, s = T[k2].y;  // e^{-i th k2} = (c, -s)
  float2* o = (float2*)(outC + (size_t)lp * 16128 + (size_t)n1 * 128);
  o[k2] = make_float2(Er + c * Or + s * Oi, Ei + c * Oi - s * Or);
}

// Stage 2: cols forward over n1 + fused highpass mask * |F| / N^2.
// Output pair (k1, k1+63) from even/odd-n1 partial sums.
__global__ __launch_bounds__(256)
void dft_cols_fwd_mask_k(const float* __restrict__ inC, float* __restrict__ outC)
{
  __shared__ float2 S[4032];   // [n1][c], c = k2-gbase
  __shared__ float2 T[126];
  const int lp = blockIdx.x >> 1, gbase = (blockIdx.x & 1) * 32;
  const int tid = threadIdx.x;
  if (tid < 126) { float s, c; sincosf(P2N * (float)tid, &s, &c); T[tid] = make_float2(c, s); }
  const float2* src = (const float2*)(inC + (size_t)lp * 16128);
  for (int e = tid; e < 4032; e += 256) {
    int n1 = e >> 5, c = e & 31;
    S[e] = src[n1 * 64 + gbase + c];
  }
  __syncthreads();
  float2* dst = (float2*)(outC + (size_t)lp * 16128);
  for (int e = tid; e < 2016; e += 256) {
    int k1 = e >> 5, c = e & 31;   // k1 in [0,62]
    int k2 = gbase + c;
    int inc = 2 * k1;
    int me = 0, mo = k1;
    float Er = 0.f, Ei = 0.f, Or = 0.f, Oi = 0.f;
    for (int u = 0; u < 63; ++u) {
      float2 s0 = S[(2 * u) * 32 + c];
      float2 t0 = T[me];
      Er += s0.x * t0.x + s0.y * t0.y;
      Ei += s0.y * t0.x - s0.x * t0.y;
      float2 s1 = S[(2 * u + 1) * 32 + c];
      float2 t1 = T[mo];
      Or += s1.x * t1.x + s1.y * t1.y;
      Oi += s1.y * t1.x - s1.x * t1.y;
      me += inc; if (me >= 126) me -= 126;
      mo += inc; if (mo >= 126) mo -= 126;
    }
    int f2 = (k2 <= 62) ? k2 : k2 - 126;
    float ar = Er + Or, ai = Ei + Oi;       // output k1   (f1 = k1)
    float br = Er - Or, bi = Ei - Oi;       // output k1+63 (f1 = k1-63)
    float sa = (k1 * k1 + f2 * f2 > 1600) ? sqrtf(ar * ar + ai * ai) * (1.f / 15876.f) : 0.f;
    int f1b = k1 - 63;
    float sb = (f1b * f1b + f2 * f2 > 1600) ? sqrtf(br * br + bi * bi) * (1.f / 15876.f) : 0.f;
    dst[(size_t)k1 * 64 + k2]        = make_float2(ar * sa, ai * sa);
    dst[(size_t)(k1 + 63) * 64 + k2] = make_float2(br * sb, bi * sb);
  }
}

// Stage 3: cols inverse over k1. Output pair (n1, n1+63) from even/odd-k1 partial sums.
__global__ __launch_bounds__(256)
void dft_cols_inv_k(const float* __restrict__ inC, float* __restrict__ outC)
{
  __shared__ float2 S[4032];   // [k1][c]
  __shared__ float2 T[126];
  const int lp = blockIdx.x >> 1, gbase = (blockIdx.x & 1) * 32;
  const int tid = threadIdx.x;
  if (tid < 126) { float s, c; sincosf(P2N * (float)tid, &s, &c); T[tid] = make_float2(c, s); }
  const float2* src = (const float2*)(inC + (size_t)lp * 16128);
  for (int e = tid; e < 4032; e += 256) {
    int k1 = e >> 5, c = e & 31;
    S[e] = src[k1 * 64 + gbase + c];
  }
  __syncthreads();
  float2* dst = (float2*)(outC + (size_t)lp * 16128);
  for (int e = tid; e < 2016; e += 256) {
    int n1 = e >> 5, c = e & 31;   // n1 in [0,62]
    int k2 = gbase + c;
    int inc = (2 * n1) % 126;
    int me = 0, mo = n1;
    float Er = 0.f, Ei = 0.f, Or = 0.f, Oi = 0.f;
    for (int u = 0; u < 63; ++u) {
      float2 s0 = S[(2 * u) * 32 + c];
      float2 t0 = T[me];
      Er += s0.x * t0.x - s0.y * t0.y;
      Ei += s0.x * t0.y + s0.y * t0.x;
      float2 s1 = S[(2 * u + 1) * 32 + c];
      float2 t1 = T[mo];
      Or += s1.x * t1.x - s1.y * t1.y;
      Oi += s1.x * t1.y + s1.y * t1.x;
      me += inc; if (me >= 126) me -= 126;
      mo += inc; if (mo >= 126) mo -= 126;
    }
    dst[(size_t)n1 * 64 + k2]        = make_float2(Er + Or, Ei + Oi);
    dst[(size_t)(n1 + 63) * 64 + k2] = make_float2(Er - Or, Ei - Oi);
  }
}

// Stage 4: rows inverse (Hermitian doubling over k2) -> |real|, mix with xc0 via fw
__global__ __launch_bounds__(128)
void dft_rows_inv_mix_k(const float* __restrict__ inC, const float* __restrict__ xc0,
                        const float* __restrict__ gb_w, float* __restrict__ out, int planeBase)
{
  __shared__ float2 Z[64];
  __shared__ float2 T[126];
  const int lp = blockIdx.x / 126, n1 = blockIdx.x % 126;
  const int tid = threadIdx.x;
  const float2* src = (const float2*)(inC + (size_t)lp * 16128 + (size_t)n1 * 128);
  if (tid < 64) Z[tid] = src[tid];
  if (tid < 126) { float s, c; sincosf(P2N * (float)tid, &s, &c); T[tid] = make_float2(c, s); }
  __syncthreads();
  const int n2 = tid;
  if (n2 < 126) {
    float a = Z[0].x + ((n2 & 1) ? -Z[63].x : Z[63].x);
    float acc = 0.f;
    int m = n2;
    for (int k2 = 1; k2 < 63; ++k2) {
      float2 z = Z[k2];
      float2 t = T[m];
      acc += z.x * t.x - z.y * t.y;
      m += n2; if (m >= 126) m -= 126;
    }
    a += 2.f * acc;
    float w0 = fmaxf(gb_w[0], 0.f), w1 = fmaxf(gb_w[1], 0.f);
    float inv = 1.f / (w0 + w1 + 1e-8f);
    size_t gi = (size_t)(planeBase + lp) * 15876 + (size_t)n1 * 126 + n2;
    out[gi] = (w0 * inv) * fabsf(a) + (w1 * inv) * xc0[gi];
  }
}

// ---------------- maxpool 2x2 stride1: 126 -> 125 ----------------
__global__ __launch_bounds__(256) void mp1_k(const float* __restrict__ in, float* __restrict__ out)
{
  int idx = blockIdx.x * 256 + threadIdx.x;
  if (idx >= 512 * 125 * 125) return;
  int x = idx % 125, y = (idx / 125) % 125, p = idx / 15625;
  const float* ip = in + (size_t)p * 15876 + (size_t)y * 126 + x;
  out[idx] = fmaxf(fmaxf(ip[0], ip[1]), fmaxf(ip[126], ip[127]));
}

// ---------------- conv3x3 stride2, valid: 125 -> 62, + bias + relu ----------------
__global__ __launch_bounds__(256)
void convgc_k(const float* __restrict__ in, const float* __restrict__ w,
              const float* __restrict__ bias, float* __restrict__ out)
{
  int idx = blockIdx.x * 256 + threadIdx.x;
  if (idx >= 8 * 64 * 62 * 62) return;
  int x = idx % 62, y = (idx / 62) % 62;
  int co = (idx / 3844) % 64, b = idx / 246016;
  float s = bias[co];
  for (int cin = 0; cin < 64; ++cin) {
    const float* ip = in + ((size_t)(b * 64 + cin) * 125 + 2 * y) * 125 + 2 * x;
    const float* wk = w + ((size_t)co * 64 + cin) * 9;
    s += ip[0]   * wk[0] + ip[1]   * wk[1] + ip[2]   * wk[2]
       + ip[125] * wk[3] + ip[126] * wk[4] + ip[127] * wk[5]
       + ip[250] * wk[6] + ip[251] * wk[7] + ip[252] * wk[8];
  }
  out[idx] = fmaxf(s, 0.f);
}

// ---------------- maxpool 2x2 stride2: 62 -> 31 ----------------
__global__ __launch_bounds__(256) void mp2_k(const float* __restrict__ in, float* __restrict__ out)
{
  int idx = blockIdx.x * 256 + threadIdx.x;
  if (idx >= 512 * 31 * 31) return;
  int x = idx % 31, y = (idx / 31) % 31, p = idx / 961;
  const float* ip = in + (size_t)p * 3844 + (size_t)(2 * y) * 62 + 2 * x;
  out[idx] = fmaxf(fmaxf(ip[0], ip[1]), fmaxf(ip[62], ip[63]));
}

// ---------------- bilinear resize 31 -> 128 ----------------
__global__ __launch_bounds__(256) void resize_k(const float* __restrict__ in, float* __restrict__ out)
{
  int idx = blockIdx.x * 256 + threadIdx.x;
  if (idx >= 512 * 128 * 128) return;
  int x = idx & 127, y = (idx >> 7) & 127, p = idx >> 14;
  float sy = (y + 0.5f) * (31.f / 128.f) - 0.5f; sy = fminf(fmaxf(sy, 0.f), 30.f);
  float sx = (x + 0.5f) * (31.f / 128.f) - 0.5f; sx = fminf(fmaxf(sx, 0.f), 30.f);
  int y0 = (int)sy; float fy = sy - (float)y0; int y1 = min(y0 + 1, 30);
  int x0 = (int)sx; float fx = sx - (float)x0; int x1 = min(x0 + 1, 30);
  const float* ip = in + (size_t)p * 961;
  float v = (1.f - fy) * ((1.f - fx) * ip[y0 * 31 + x0] + fx * ip[y0 * 31 + x1])
          + fy         * ((1.f - fx) * ip[y1 * 31 + x0] + fx * ip[y1 * 31 + x1]);
  out[idx] = v;
}

// ---------------- 1x1 conv (w_gc2 + bias) + log_softmax over 64 channels ----------------
__global__ __launch_bounds__(256)
void pwlsm_k(const float* __restrict__ in, const float* __restrict__ w,
             const float* __restrict__ bias, float* __restrict__ out)
{
  __shared__ float zs[64 * 256];
  int idx = blockIdx.x * 256 + threadIdx.x;
  int b = idx >> 14, px = idx & 16383;
  const float* ip = in + ((size_t)b << 20) + px;
  float v[64];
#pragma unroll
  for (int i = 0; i < 64; ++i) v[i] = ip[(size_t)i << 14];
  float m = -1e30f;
  for (int co = 0; co < 64; ++co) {
    float s = bias[co];
    const float* wk = w + co * 64;
#pragma unroll
    for (int i = 0; i < 64; ++i) s += v[i] * wk[i];
    zs[co * 256 + threadIdx.x] = s;
    m = fmaxf(m, s);
  }
  float sum = 0.f;
  for (int co = 0; co < 64; ++co) sum += __expf(zs[co * 256 + threadIdx.x] - m);
  float lse = m + __logf(sum);
  float* op = out + ((size_t)b << 20) + px;
  for (int co = 0; co < 64; ++co) op[(size_t)co << 14] = zs[co * 256 + threadIdx.x] - lse;
}

// ---------------- windowed attention, conflict-free layouts, per-head qkv ----------------
// LDS: xt[cin][pix] 16KB + q/k/v[d][i] 6KB + P[j][i] 16KB + invr 256B = 39.2KB -> 4 blocks/CU
__global__ __launch_bounds__(256)
void attn_k(const float* __restrict__ x, const float* __restrict__ wqkv,
            const float* __restrict__ rpbt, float* __restrict__ o_out)
{
  __shared__ float xt[4096];
  __shared__ float qs[512], ks[512], vs[512];
  __shared__ float P[4096];
  __shared__ float invr[64];
  const int tid = threadIdx.x;
  const int b = blockIdx.x >> 8, gy = (blockIdx.x >> 4) & 15, gx = blockIdx.x & 15;
  const int y0 = gy * 8, x0 = gx * 8;
  const int i = tid & 63, g = tid >> 6;   // pixel i, lane-group g in [0,4)

  for (int e = tid; e < 4096; e += 256) {
    int cin = e >> 6, pix = e & 63;
    xt[e] = x[((size_t)(b * 64 + cin) * 128 + (y0 + (pix >> 3))) * 128 + x0 + (pix & 7)];
  }
  __syncthreads();

  for (int h = 0; h < 8; ++h) {
    // qkv for head h: each thread computes 6 channels at its pixel i
    const float* rowp[6];
#pragma unroll
    for (int r = 0; r < 6; ++r) {
      int ch24 = g + r * 4;                  // 0..23
      int comp = ch24 >> 3, d = ch24 & 7;
      rowp[r] = wqkv + (size_t)(comp * 64 + h * 8 + d) * 64;
    }
    float acc[6];
#pragma unroll
    for (int r = 0; r < 6; ++r) acc[r] = 0.f;
    for (int cb = 0; cb < 64; cb += 4) {
      float xv0 = xt[(cb + 0) * 64 + i];
      float xv1 = xt[(cb + 1) * 64 + i];
      float xv2 = xt[(cb + 2) * 64 + i];
      float xv3 = xt[(cb + 3) * 64 + i];
#pragma unroll
      for (int r = 0; r < 6; ++r) {
        float4 w = *(const float4*)(rowp[r] + cb);
        acc[r] += xv0 * w.x + xv1 * w.y + xv2 * w.z + xv3 * w.w;
      }
    }
#pragma unroll
    for (int r = 0; r < 6; ++r) {
      int ch24 = g + r * 4;
      int comp = ch24 >> 3, d = ch24 & 7;
      float* dst = (comp == 0) ? qs : (comp == 1) ? ks : vs;
      dst[d * 64 + i] = acc[r];
    }
    __syncthreads();
    // dots: thread computes P[j][i] for 16 j values (q in registers)
    float qv[8];
#pragma unroll
    for (int d = 0; d < 8; ++d) qv[d] = qs[d * 64 + i];
    const float* rb = rpbt + h * 4096;
    for (int jj = 0; jj < 16; ++jj) {
      int j = g + jj * 4;
      float s = 0.f;
#pragma unroll
      for (int d = 0; d < 8; ++d) s += qv[d] * ks[d * 64 + j];
      P[j * 64 + i] = s * ATT_SCALE + rb[j * 64 + i];
    }
    __syncthreads();
    if (tid < 64) {
      float m = -1e30f;
      for (int j = 0; j < 64; ++j) m = fmaxf(m, P[j * 64 + tid]);
      float sum = 0.f;
      for (int j = 0; j < 64; ++j) { float p = __expf(P[j * 64 + tid] - m); P[j * 64 + tid] = p; sum += p; }
      invr[tid] = 1.f / sum;
    }
    __syncthreads();
    // PV: thread computes o[g][i] and o[g+4][i], writes straight to global
    {
      float s0 = 0.f, s1 = 0.f;
      for (int j = 0; j < 64; ++j) {
        float p = P[j * 64 + i];
        s0 += p * vs[g * 64 + j];
        s1 += p * vs[(g + 4) * 64 + j];
      }
      float inv = invr[i];
      int row = y0 + (i >> 3), col = x0 + (i & 7);
      o_out[((size_t)(b * 64 + h * 8 + g) * 128 + row) * 128 + col] = s0 * inv;
      o_out[((size_t)(b * 64 + h * 8 + g + 4) * 128 + row) * 128 + col] = s1 * inv;
    }
    __syncthreads();
  }
}

// ------- directional avg pools (reflect+zero pad semantics) + add local -------
__global__ __launch_bounds__(256)
void avgadd_k(const float* __restrict__ o, const float* __restrict__ loc, float* __restrict__ out)
{
  int idx = blockIdx.x * 256 + threadIdx.x;
  if (idx >= 8388608) return;
  int x = idx & 127, y = (idx >> 7) & 127;
  size_t p = (size_t)(idx >> 14);
  const float* op = o + (p << 14);
  float s1 = 0.f, s2 = 0.f;
#pragma unroll
  for (int t = 0; t < 8; ++t) {
    int r = y - 3 + t;
    if (r >= 0 && r <= 128) { int rr = (r == 128) ? 126 : r; s1 += op[rr * 128 + x]; }
    int cc = x - 3 + t;
    if (cc >= 0 && cc <= 128) { int ss = (cc == 128) ? 126 : cc; s2 += op[y * 128 + ss]; }
  }
  out[idx] = 0.125f * (s1 + s2) + loc[idx];
}

// ---------------- depthwise 8x8 conv (pad_out + pad3, zero) + BN ----------------
__global__ __launch_bounds__(256)
void dw_k(const float* __restrict__ in, const float* __restrict__ w,
          const float* __restrict__ g, const float* __restrict__ bb, float* __restrict__ out)
{
  __shared__ float t[23 * 23];
  const int tid = threadIdx.x;
  const int tx = tid & 15, ty = tid >> 4;
  const int x0 = blockIdx.x * 16, y0 = blockIdx.y * 16;
  const int pc = blockIdx.z;
  const int c = pc & 63;
  const float* ip = in + (size_t)pc * 16384;
  for (int e = tid; e < 529; e += 256) {
    int yy = e / 23, xx = e % 23;
    int iy = y0 + yy - 3, ix = x0 + xx - 3;
    t[e] = (iy >= 0 && iy < 128 && ix >= 0 && ix < 128) ? ip[iy * 128 + ix] : 0.f;
  }
  __syncthreads();
  const float* wk = w + c * 64;
  float s = 0.f;
#pragma unroll
  for (int ky = 0; ky < 8; ++ky)
#pragma unroll
    for (int kx = 0; kx < 8; ++kx)
      s += t[(ty + ky) * 23 + tx + kx] * wk[ky * 8 + kx];
  out[(size_t)pc * 16384 + (y0 + ty) * 128 + x0 + tx] = s * (g[c] * BN_SC) + bb[c];
}

// ---------------- final 1x1 conv (w_pw, no bias) ----------------
__global__ __launch_bounds__(256)
void pw_k(const float* __restrict__ in, const float* __restrict__ w, float* __restrict__ out)
{
  int idx = blockIdx.x * 256 + threadIdx.x;
  int b = idx >> 14, px = idx & 16383;
  const float* ip = in + ((size_t)b << 20) + px;
  float v[64];
#pragma unroll
  for (int i = 0; i < 64; ++i) v[i] = ip[(size_t)i << 14];
  float* op = out + ((size_t)b << 20) + px;
  for (int co = 0; co < 64; ++co) {
    const float* wk = w + co * 64;
    float s = 0.f;
#pragma unroll
    for (int i = 0; i < 64; ++i) s += v[i] * wk[i];
    op[(size_t)co << 14] = s;
  }
}

// =======================================================================
extern "C" void kernel_launch(void* const* d_in, const int* in_sizes, int n_in,
                              void* d_out, int out_size, void* d_ws, size_t ws_size,
                              hipStream_t stream)
{
  const float* x      = (const float*)d_in[0];
  const float* w_qkv  = (const float*)d_in[1];
  const float* w_l1   = (const float*)d_in[2];
  const float* g_l1   = (const float*)d_in[3];
  const float* b_l1   = (const float*)d_in[4];
  const float* w_l2   = (const float*)d_in[5];
  const float* g_l2   = (const float*)d_in[6];
  const float* b_l2   = (const float*)d_in[7];
  const float* f_cos  = (const float*)d_in[8];
  const float* f_sin  = (const float*)d_in[9];
  const float* gb_b1  = (const float*)d_in[10];
  const float* gb_b2  = (const float*)d_in[11];
  const float* gb_w   = (const float*)d_in[12];
  const float* w_post = (const float*)d_in[13];
  const float* g_post = (const float*)d_in[14];
  const float* b_post = (const float*)d_in[15];
  const float* w_gc   = (const float*)d_in[16];
  const float* b_gc   = (const float*)d_in[17];
  const float* w_gc1  = (const float*)d_in[18];
  const float* b_gc1  = (const float*)d_in[19];
  const float* w_gc2  = (const float*)d_in[20];
  const float* b_gc2  = (const float*)d_in[21];
  const float* rpb    = (const float*)d_in[22];
  const float* w_dw   = (const float*)d_in[23];
  const float* g_proj = (const float*)d_in[24];
  const float* b_proj = (const float*)d_in[25];
  const float* w_pw   = (const float*)d_in[26];
  const int*   relidx = (const int*)d_in[27];
  float* out = (float*)d_out;

  char* ws = (char*)d_ws;
  float* R1   = (float*)(ws + 0);                       // 32 MB
  float* R2   = (float*)(ws + 33554432);                // 32 MB
  float* R3   = (float*)(ws + 67108864);                // conv-gc out / out0 (<=32MB)
  float* C1   = R3;                                     // 15.75 MB (compact complex)
  float* C2   = (float*)(ws + 67108864 + 16515072);     // 15.75 MB
  float* XC5  = (float*)(ws + 67108864 + 33030144);     // 1.97 MB
  float* RPBT = (float*)(ws + 67108864 + 34998272);     // 128 KB
  float* W1S  = (float*)(ws + 67108864);                // prep (dead before FFT)
  float* W2S  = (float*)(ws + 67108864 + 147456);
  float* BLS  = (float*)(ws + 67108864 + 163840);

  // 1. fold BN into local-branch weights
  prep_k<<<144, 256, 0, stream>>>(w_l1, g_l1, b_l1, w_l2, g_l2, b_l2, W1S, W2S, BLS);
  // 2. local_pre = bn(conv1x1) + bn(conv3x3)  -> R1
  conv3x3_k<M_LOCAL, 128, 128, 1><<<dim3(64, 8, 4), 256, 0, stream>>>(x, W1S, W2S, BLS, nullptr, R1);
  // 3. gabor conv (valid, cos||sin + biases)  -> R2 (xc0, 126x126)
  conv3x3_k<M_GABOR, 128, 126, 0><<<dim3(64, 8, 4), 256, 0, stream>>>(R1, f_cos, f_sin, gb_b1, gb_b2, R2);
  // 4. fft_h + fw-mix, 2 chunks of 256 planes -> R1 (xc1)
  for (int chunk = 0; chunk < 2; ++chunk) {
    int pb = chunk * 256;
    dft_rows_fwd_k<<<256 * 126, 64, 0, stream>>>(R2, C1, pb);
    dft_cols_fwd_mask_k<<<512, 256, 0, stream>>>(C1, C2);
    dft_cols_inv_k<<<512, 256, 0, stream>>>(C2, C1);
    dft_rows_inv_mix_k<<<256 * 126, 128, 0, stream>>>(C1, R2, gb_w, R1, pb);
  }
  // 4.5 pre-gather rpb bias table (C2 region free from here on for out0 overlap later)
  rpbprep_k<<<128, 256, 0, stream>>>(rpb, relidx, RPBT);
  // 5. relu6(bn(conv3x3 w_post)) -> R2 (xc2)
  conv3x3_k<M_BNRELU6, 126, 126, 1><<<dim3(64, 8, 4), 256, 0, stream>>>(R1, w_post, nullptr, g_post, b_post, R2);
  // 6. maxpool 2x2 s1 -> R1 (125^2)
  mp1_k<<<31250, 256, 0, stream>>>(R2, R1);
  // 7. relu(conv3x3 s2 w_gc) -> R3 (62^2)
  convgc_k<<<7688, 256, 0, stream>>>(R1, w_gc, b_gc, R3);
  // 8. maxpool 2x2 s2 -> XC5 (31^2)
  mp2_k<<<1922, 256, 0, stream>>>(R3, XC5);
  // 9. bilinear resize 31 -> 128 -> R1 (xc6)
  resize_k<<<32768, 256, 0, stream>>>(XC5, R1);
  // 10. relu(conv3x3 w_gc1 + b) -> R2 (xc7)
  conv3x3_k<M_BIASRELU, 128, 128, 1><<<dim3(64, 8, 4), 256, 0, stream>>>(R1, w_gc1, nullptr, b_gc1, nullptr, R2);
  // 11. 1x1 conv w_gc2 + log_softmax -> R1 (local)
  pwlsm_k<<<512, 256, 0, stream>>>(R2, w_gc2, b_gc2, R1);
  // 12. window attention -> R2 (o)
  attn_k<<<2048, 256, 0, stream>>>(x, w_qkv, RPBT, R2);
  // 13. ox + oy + local -> R3 (out0; overlaps dead C1/C2 — safe, rpbt is beyond 33.55MB)
  avgadd_k<<<32768, 256, 0, stream>>>(R2, R1, R3);
  // 14. depthwise 8x8 + bn -> R2
  dw_k<<<dim3(8, 8, 512), 256, 0, stream>>>(R3, w_dw, g_proj, b_proj, R2);
  // 15. 1x1 conv w_pw -> d_out
  pw_k<<<512, 256, 0, stream>>>(R2, w_pw, out);
  (void)in_sizes; (void)n_in; (void)out_size; (void)ws_size;
}

// Round 6
// 2887.682 us; speedup vs baseline: 1.4871x; 1.0112x over previous
//
#include <hip/hip_runtime.h>
#include <math.h>

#define BN_SC 0.9999950000375f
#define P2N   (6.283185307179586f / 126.f)
#define ATT_SCALE 0.35355339059327373f

enum { M_LOCAL = 0, M_GABOR = 1, M_BNRELU6 = 2, M_BIASRELU = 3 };

// ---------------- weight prep: fold BN scale into w_l1 / w_l2 ----------------
__global__ __launch_bounds__(256) void prep_k(
    const float* __restrict__ w_l1, const float* __restrict__ g_l1, const float* __restrict__ b_l1,
    const float* __restrict__ w_l2, const float* __restrict__ g_l2, const float* __restrict__ b_l2,
    float* __restrict__ w1s, float* __restrict__ w2s, float* __restrict__ bs)
{
  int i = blockIdx.x * 256 + threadIdx.x;
  if (i < 36864) w1s[i] = w_l1[i] * (g_l1[i / 576] * BN_SC);
  if (i < 4096)  w2s[i] = w_l2[i] * (g_l2[i / 64] * BN_SC);
  if (i < 64)    bs[i]  = b_l1[i] + b_l2[i];
}

// ------------- rpb bias pre-gather: rpbt[h][j*64+i] = rpb[relidx[i*64+j]*8+h] -------------
__global__ __launch_bounds__(256) void rpbprep_k(
    const float* __restrict__ rpb, const int* __restrict__ relidx, float* __restrict__ rpbt)
{
  int idx = blockIdx.x * 256 + threadIdx.x; // 32768
  int h = idx >> 12, r = idx & 4095, j = r >> 6, i = r & 63;
  rpbt[idx] = rpb[relidx[i * 64 + j] * 8 + h];
}

// ---------------- fp32 3x3 conv, 64->64 ch, LDS-staged WEIGHTS + activations ----------------
// Identical numerics/accumulation order to the round-2-proven conv3x3_k; only the weight
// source changed from per-thread global reads (176MB FETCH/dispatch) to one LDS stage per
// block with float4 broadcast reads (pitch 12 floats = 48B -> every (cin,co) row 16B-aligned).
// block: 256 thr = 16x16 pixels; grid (64, B, 4): blockIdx.x = tile, .y = batch, .z = cout/16
template<int MODE, int IN_HW, int OUT_HW, int PAD>
__global__ __launch_bounds__(256)
void conv3x3f_k(const float* __restrict__ in, const float* __restrict__ wa,
                const float* __restrict__ wb, const float* __restrict__ pa,
                const float* __restrict__ pb, float* __restrict__ out)
{
  __shared__ float wsm[12288];    // [cin 64][co 16][12]  (slots 9..11 pad; 9 = 1x1 for LOCAL)
  __shared__ float tile[8 * 324]; // 8 cin x 18x18
  const int tid = threadIdx.x;
  const int tx = tid & 15, ty = tid >> 4;
  const int nt = (OUT_HW + 15) >> 4;
  const int bx = blockIdx.x % nt, by = blockIdx.x / nt;
  const int b = blockIdx.y, cg = blockIdx.z;
  const int ox0 = bx * 16, oy0 = by * 16;

  // ---- stage weights for this block's 16 couts ----
  for (int e = tid; e < 9216; e += 256) {
    int o = e % 9, q = e / 9;
    int co = q & 15, cin = q >> 4;
    int c = cg * 16 + co;
    float v;
    if (MODE == M_GABOR)
      v = (c < 32) ? wa[((size_t)c * 64 + cin) * 9 + o]
                   : wb[((size_t)(c - 32) * 64 + cin) * 9 + o];
    else
      v = wa[((size_t)c * 64 + cin) * 9 + o];
    wsm[(cin * 16 + co) * 12 + o] = v;
  }
  if (MODE == M_LOCAL) {
    for (int e = tid; e < 1024; e += 256) {
      int co = e & 15, cin = e >> 4;
      wsm[(cin * 16 + co) * 12 + 9] = wb[(size_t)(cg * 16 + co) * 64 + cin];
    }
  }

  float acc[16];
#pragma unroll
  for (int i = 0; i < 16; ++i) acc[i] = 0.f;

  for (int cc = 0; cc < 64; cc += 8) {
    __syncthreads();
    for (int e = tid; e < 8 * 324; e += 256) {
      int ci = e / 324, r = e % 324;
      int yy = r / 18, xx = r % 18;
      int iy = oy0 + yy - PAD, ix = ox0 + xx - PAD;
      float v = 0.f;
      if (iy >= 0 && iy < IN_HW && ix >= 0 && ix < IN_HW)
        v = in[((size_t)(b * 64 + cc + ci) * IN_HW + iy) * IN_HW + ix];
      tile[ci * 324 + r] = v;
    }
    __syncthreads();
    for (int ci = 0; ci < 8; ++ci) {
      float v[9];
#pragma unroll
      for (int dy = 0; dy < 3; ++dy)
#pragma unroll
        for (int dx = 0; dx < 3; ++dx)
          v[dy * 3 + dx] = tile[ci * 324 + (ty + dy) * 18 + (tx + dx)];
      const float* wkb = wsm + ((cc + ci) * 16) * 12;
#pragma unroll
      for (int co = 0; co < 16; ++co) {
        const float* wk = wkb + co * 12;
        float4 w0 = *(const float4*)(wk);
        float4 w1 = *(const float4*)(wk + 4);
        float4 w2 = *(const float4*)(wk + 8);
        float s = v[0]*w0.x + v[1]*w0.y + v[2]*w0.z
                + v[3]*w0.w + v[4]*w1.x + v[5]*w1.y
                + v[6]*w1.z + v[7]*w1.w + v[8]*w2.x;
        if (MODE == M_LOCAL) s += v[4] * w2.y;
        acc[co] += s;
      }
    }
  }
  const int oy = oy0 + ty, ox = ox0 + tx;
  if (oy < OUT_HW && ox < OUT_HW) {
#pragma unroll
    for (int co = 0; co < 16; ++co) {
      const int c = cg * 16 + co;
      float r = acc[co];
      if (MODE == M_LOCAL)        r += pa[c];
      else if (MODE == M_GABOR)   r += (c < 32) ? pa[c] : pb[c - 32];
      else if (MODE == M_BNRELU6) { r = r * (pa[c] * BN_SC) + pb[c]; r = fminf(fmaxf(r, 0.f), 6.f); }
      else                        r = fmaxf(r + pa[c], 0.f);
      out[((size_t)(b * 64 + c) * OUT_HW + oy) * OUT_HW + ox] = r;
    }
  }
}

// ======================= DFT (126-pt), table-based, Hermitian-half =======================

__global__ __launch_bounds__(64)
void dft_rows_fwd_k(const float* __restrict__ in, float* __restrict__ outC, int planeBase)
{
  __shared__ float2 r2[63];
  __shared__ float2 T[126];
  const int lp = blockIdx.x / 126, n1 = blockIdx.x % 126;
  const int tid = threadIdx.x;
  const float2* row = (const float2*)(in + (size_t)(planeBase + lp) * 15876 + (size_t)n1 * 126);
  if (tid < 63) r2[tid] = row[tid];
  for (int e = tid; e < 126; e += 64) { float s, c; sincosf(P2N * (float)e, &s, &c); T[e] = make_float2(c, s); }
  __syncthreads();
  const int k2 = tid;
  const int inc = (2 * k2) % 126;
  int m = 0;
  float Er = 0.f, Ei = 0.f, Or = 0.f, Oi = 0.f;
  for (int n = 0; n < 63; ++n) {
    float2 rv = r2[n];
    float2 t = T[m];
    Er += rv.x * t.x; Ei -= rv.x * t.y;
    Or += rv.y * t.x; Oi -= rv.y * t.y;
    m += inc; if (m >= 126) m -= 126;
  }
  float c = T[k2].x, s = T[k2].y;
  float2* o = (float2*)(outC + (size_t)lp * 16128 + (size_t)n1 * 128);
  o[k2] = make_float2(Er + c * Or + s * Oi, Ei + c * Oi - s * Or);
}

__global__ __launch_bounds__(256)
void dft_cols_fwd_mask_k(const float* __restrict__ inC, float* __restrict__ outC)
{
  __shared__ float2 S[4032];
  __shared__ float2 T[126];
  const int lp = blockIdx.x >> 1, gbase = (blockIdx.x & 1) * 32;
  const int tid = threadIdx.x;
  if (tid < 126) { float s, c; sincosf(P2N * (float)tid, &s, &c); T[tid] = make_float2(c, s); }
  const float2* src = (const float2*)(inC + (size_t)lp * 16128);
  for (int e = tid; e < 4032; e += 256) {
    int n1 = e >> 5, c = e & 31;
    S[e] = src[n1 * 64 + gbase + c];
  }
  __syncthreads();
  float2* dst = (float2*)(outC + (size_t)lp * 16128);
  for (int e = tid; e < 2016; e += 256) {
    int k1 = e >> 5, c = e & 31;
    int k2 = gbase + c;
    int inc = 2 * k1;
    int me = 0, mo = k1;
    float Er = 0.f, Ei = 0.f, Or = 0.f, Oi = 0.f;
    for (int u = 0; u < 63; ++u) {
      float2 s0 = S[(2 * u) * 32 + c];
      float2 t0 = T[me];
      Er += s0.x * t0.x + s0.y * t0.y;
      Ei += s0.y * t0.x - s0.x * t0.y;
      float2 s1 = S[(2 * u + 1) * 32 + c];
      float2 t1 = T[mo];
      Or += s1.x * t1.x + s1.y * t1.y;
      Oi += s1.y * t1.x - s1.x * t1.y;
      me += inc; if (me >= 126) me -= 126;
      mo += inc; if (mo >= 126) mo -= 126;
    }
    int f2 = (k2 <= 62) ? k2 : k2 - 126;
    float ar = Er + Or, ai = Ei + Oi;
    float br = Er - Or, bi = Ei - Oi;
    float sa = (k1 * k1 + f2 * f2 > 1600) ? sqrtf(ar * ar + ai * ai) * (1.f / 15876.f) : 0.f;
    int f1b = k1 - 63;
    float sb = (f1b * f1b + f2 * f2 > 1600) ? sqrtf(br * br + bi * bi) * (1.f / 15876.f) : 0.f;
    dst[(size_t)k1 * 64 + k2]        = make_float2(ar * sa, ai * sa);
    dst[(size_t)(k1 + 63) * 64 + k2] = make_float2(br * sb, bi * sb);
  }
}

__global__ __launch_bounds__(256)
void dft_cols_inv_k(const float* __restrict__ inC, float* __restrict__ outC)
{
  __shared__ float2 S[4032];
  __shared__ float2 T[126];
  const int lp = blockIdx.x >> 1, gbase = (blockIdx.x & 1) * 32;
  const int tid = threadIdx.x;
  if (tid < 126) { float s, c; sincosf(P2N * (float)tid, &s, &c); T[tid] = make_float2(c, s); }
  const float2* src = (const float2*)(inC + (size_t)lp * 16128);
  for (int e = tid; e < 4032; e += 256) {
    int k1 = e >> 5, c = e & 31;
    S[e] = src[k1 * 64 + gbase + c];
  }
  __syncthreads();
  float2* dst = (float2*)(outC + (size_t)lp * 16128);
  for (int e = tid; e < 2016; e += 256) {
    int n1 = e >> 5, c = e & 31;
    int k2 = gbase + c;
    int inc = (2 * n1) % 126;
    int me = 0, mo = n1;
    float Er = 0.f, Ei = 0.f, Or = 0.f, Oi = 0.f;
    for (int u = 0; u < 63; ++u) {
      float2 s0 = S[(2 * u) * 32 + c];
      float2 t0 = T[me];
      Er += s0.x * t0.x - s0.y * t0.y;
      Ei += s0.x * t0.y + s0.y * t0.x;
      float2 s1 = S[(2 * u + 1) * 32 + c];
      float2 t1 = T[mo];
      Or += s1.x * t1.x - s1.y * t1.y;
      Oi += s1.x * t1.y + s1.y * t1.x;
      me += inc; if (me >= 126) me -= 126;
      mo += inc; if (mo >= 126) mo -= 126;
    }
    dst[(size_t)n1 * 64 + k2]        = make_float2(Er + Or, Ei + Oi);
    dst[(size_t)(n1 + 63) * 64 + k2] = make_float2(Er - Or, Ei - Oi);
  }
}

__global__ __launch_bounds__(128)
void dft_rows_inv_mix_k(const float* __restrict__ inC, const float* __restrict__ xc0,
                        const float* __restrict__ gb_w, float* __restrict__ out, int planeBase)
{
  __shared__ float2 Z[64];
  __shared__ float2 T[126];
  const int lp = blockIdx.x / 126, n1 = blockIdx.x % 126;
  const int tid = threadIdx.x;
  const float2* src = (const float2*)(inC + (size_t)lp * 16128 + (size_t)n1 * 128);
  if (tid < 64) Z[tid] = src[tid];
  if (tid < 126) { float s, c; sincosf(P2N * (float)tid, &s, &c); T[tid] = make_float2(c, s); }
  __syncthreads();
  const int n2 = tid;
  if (n2 < 126) {
    float a = Z[0].x + ((n2 & 1) ? -Z[63].x : Z[63].x);
    float acc = 0.f;
    int m = n2;
    for (int k2 = 1; k2 < 63; ++k2) {
      float2 z = Z[k2];
      float2 t = T[m];
      acc += z.x * t.x - z.y * t.y;
      m += n2; if (m >= 126) m -= 126;
    }
    a += 2.f * acc;
    float w0 = fmaxf(gb_w[0], 0.f), w1 = fmaxf(gb_w[1], 0.f);
    float inv = 1.f / (w0 + w1 + 1e-8f);
    size_t gi = (size_t)(planeBase + lp) * 15876 + (size_t)n1 * 126 + n2;
    out[gi] = (w0 * inv) * fabsf(a) + (w1 * inv) * xc0[gi];
  }
}

// ---------------- maxpool 2x2 stride1: 126 -> 125 ----------------
__global__ __launch_bounds__(256) void mp1_k(const float* __restrict__ in, float* __restrict__ out)
{
  int idx = blockIdx.x * 256 + threadIdx.x;
  if (idx >= 512 * 125 * 125) return;
  int x = idx % 125, y = (idx / 125) % 125, p = idx / 15625;
  const float* ip = in + (size_t)p * 15876 + (size_t)y * 126 + x;
  out[idx] = fmaxf(fmaxf(ip[0], ip[1]), fmaxf(ip[126], ip[127]));
}

// ---------------- conv3x3 stride2, valid: 125 -> 62, + bias + relu ----------------
__global__ __launch_bounds__(256)
void convgc_k(const float* __restrict__ in, const float* __restrict__ w,
              const float* __restrict__ bias, float* __restrict__ out)
{
  int idx = blockIdx.x * 256 + threadIdx.x;
  if (idx >= 8 * 64 * 62 * 62) return;
  int x = idx % 62, y = (idx / 62) % 62;
  int co = (idx / 3844) % 64, b = idx / 246016;
  float s = bias[co];
  for (int cin = 0; cin < 64; ++cin) {
    const float* ip = in + ((size_t)(b * 64 + cin) * 125 + 2 * y) * 125 + 2 * x;
    const float* wk = w + ((size_t)co * 64 + cin) * 9;
    s += ip[0]   * wk[0] + ip[1]   * wk[1] + ip[2]   * wk[2]
       + ip[125] * wk[3] + ip[126] * wk[4] + ip[127] * wk[5]
       + ip[250] * wk[6] + ip[251] * wk[7] + ip[252] * wk[8];
  }
  out[idx] = fmaxf(s, 0.f);
}

// ---------------- maxpool 2x2 stride2: 62 -> 31 ----------------
__global__ __launch_bounds__(256) void mp2_k(const float* __restrict__ in, float* __restrict__ out)
{
  int idx = blockIdx.x * 256 + threadIdx.x;
  if (idx >= 512 * 31 * 31) return;
  int x = idx % 31, y = (idx / 31) % 31, p = idx / 961;
  const float* ip = in + (size_t)p * 3844 + (size_t)(2 * y) * 62 + 2 * x;
  out[idx] = fmaxf(fmaxf(ip[0], ip[1]), fmaxf(ip[62], ip[63]));
}

// ---------------- bilinear resize 31 -> 128 ----------------
__global__ __launch_bounds__(256) void resize_k(const float* __restrict__ in, float* __restrict__ out)
{
  int idx = blockIdx.x * 256 + threadIdx.x;
  if (idx >= 512 * 128 * 128) return;
  int x = idx & 127, y = (idx >> 7) & 127, p = idx >> 14;
  float sy = (y + 0.5f) * (31.f / 128.f) - 0.5f; sy = fminf(fmaxf(sy, 0.f), 30.f);
  float sx = (x + 0.5f) * (31.f / 128.f) - 0.5f; sx = fminf(fmaxf(sx, 0.f), 30.f);
  int y0 = (int)sy; float fy = sy - (float)y0; int y1 = min(y0 + 1, 30);
  int x0 = (int)sx; float fx = sx - (float)x0; int x1 = min(x0 + 1, 30);
  const float* ip = in + (size_t)p * 961;
  float v = (1.f - fy) * ((1.f - fx) * ip[y0 * 31 + x0] + fx * ip[y0 * 31 + x1])
          + fy         * ((1.f - fx) * ip[y1 * 31 + x0] + fx * ip[y1 * 31 + x1]);
  out[idx] = v;
}

// ---------------- 1x1 conv (w_gc2 + bias) + log_softmax over 64 channels ----------------
__global__ __launch_bounds__(256)
void pwlsm_k(const float* __restrict__ in, const float* __restrict__ w,
             const float* __restrict__ bias, float* __restrict__ out)
{
  __shared__ float zs[64 * 256];
  int idx = blockIdx.x * 256 + threadIdx.x;
  int b = idx >> 14, px = idx & 16383;
  const float* ip = in + ((size_t)b << 20) + px;
  float v[64];
#pragma unroll
  for (int i = 0; i < 64; ++i) v[i] = ip[(size_t)i << 14];
  float m = -1e30f;
  for (int co = 0; co < 64; ++co) {
    float s = bias[co];
    const float* wk = w + co * 64;
#pragma unroll
    for (int i = 0; i < 64; ++i) s += v[i] * wk[i];
    zs[co * 256 + threadIdx.x] = s;
    m = fmaxf(m, s);
  }
  float sum = 0.f;
  for (int co = 0; co < 64; ++co) sum += __expf(zs[co * 256 + threadIdx.x] - m);
  float lse = m + __logf(sum);
  float* op = out + ((size_t)b << 20) + px;
  for (int co = 0; co < 64; ++co) op[(size_t)co << 14] = zs[co * 256 + threadIdx.x] - lse;
}

// ---------------- windowed attention, conflict-free layouts, per-head qkv ----------------
__global__ __launch_bounds__(256)
void attn_k(const float* __restrict__ x, const float* __restrict__ wqkv,
            const float* __restrict__ rpbt, float* __restrict__ o_out)
{
  __shared__ float xt[4096];
  __shared__ float qs[512], ks[512], vs[512];
  __shared__ float P[4096];
  __shared__ float invr[64];
  const int tid = threadIdx.x;
  const int b = blockIdx.x >> 8, gy = (blockIdx.x >> 4) & 15, gx = blockIdx.x & 15;
  const int y0 = gy * 8, x0 = gx * 8;
  const int i = tid & 63, g = tid >> 6;

  for (int e = tid; e < 4096; e += 256) {
    int cin = e >> 6, pix = e & 63;
    xt[e] = x[((size_t)(b * 64 + cin) * 128 + (y0 + (pix >> 3))) * 128 + x0 + (pix & 7)];
  }
  __syncthreads();

  for (int h = 0; h < 8; ++h) {
    const float* rowp[6];
#pragma unroll
    for (int r = 0; r < 6; ++r) {
      int ch24 = g + r * 4;
      int comp = ch24 >> 3, d = ch24 & 7;
      rowp[r] = wqkv + (size_t)(comp * 64 + h * 8 + d) * 64;
    }
    float acc[6];
#pragma unroll
    for (int r = 0; r < 6; ++r) acc[r] = 0.f;
    for (int cb = 0; cb < 64; cb += 4) {
      float xv0 = xt[(cb + 0) * 64 + i];
      float xv1 = xt[(cb + 1) * 64 + i];
      float xv2 = xt[(cb + 2) * 64 + i];
      float xv3 = xt[(cb + 3) * 64 + i];
#pragma unroll
      for (int r = 0; r < 6; ++r) {
        float4 w = *(const float4*)(rowp[r] + cb);
        acc[r] += xv0 * w.x + xv1 * w.y + xv2 * w.z + xv3 * w.w;
      }
    }
#pragma unroll
    for (int r = 0; r < 6; ++r) {
      int ch24 = g + r * 4;
      int comp = ch24 >> 3, d = ch24 & 7;
      float* dst = (comp == 0) ? qs : (comp == 1) ? ks : vs;
      dst[d * 64 + i] = acc[r];
    }
    __syncthreads();
    float qv[8];
#pragma unroll
    for (int d = 0; d < 8; ++d) qv[d] = qs[d * 64 + i];
    const float* rb = rpbt + h * 4096;
    for (int jj = 0; jj < 16; ++jj) {
      int j = g + jj * 4;
      float s = 0.f;
#pragma unroll
      for (int d = 0; d < 8; ++d) s += qv[d] * ks[d * 64 + j];
      P[j * 64 + i] = s * ATT_SCALE + rb[j * 64 + i];
    }
    __syncthreads();
    if (tid < 64) {
      float m = -1e30f;
      for (int j = 0; j < 64; ++j) m = fmaxf(m, P[j * 64 + tid]);
      float sum = 0.f;
      for (int j = 0; j < 64; ++j) { float p = __expf(P[j * 64 + tid] - m); P[j * 64 + tid] = p; sum += p; }
      invr[tid] = 1.f / sum;
    }
    __syncthreads();
    {
      float s0 = 0.f, s1 = 0.f;
      for (int j = 0; j < 64; ++j) {
        float p = P[j * 64 + i];
        s0 += p * vs[g * 64 + j];
        s1 += p * vs[(g + 4) * 64 + j];
      }
      float inv = invr[i];
      int row = y0 + (i >> 3), col = x0 + (i & 7);
      o_out[((size_t)(b * 64 + h * 8 + g) * 128 + row) * 128 + col] = s0 * inv;
      o_out[((size_t)(b * 64 + h * 8 + g + 4) * 128 + row) * 128 + col] = s1 * inv;
    }
    __syncthreads();
  }
}

// ------- directional avg pools (reflect+zero pad semantics) + add local -------
__global__ __launch_bounds__(256)
void avgadd_k(const float* __restrict__ o, const float* __restrict__ loc, float* __restrict__ out)
{
  int idx = blockIdx.x * 256 + threadIdx.x;
  if (idx >= 8388608) return;
  int x = idx & 127, y = (idx >> 7) & 127;
  size_t p = (size_t)(idx >> 14);
  const float* op = o + (p << 14);
  float s1 = 0.f, s2 = 0.f;
#pragma unroll
  for (int t = 0; t < 8; ++t) {
    int r = y - 3 + t;
    if (r >= 0 && r <= 128) { int rr = (r == 128) ? 126 : r; s1 += op[rr * 128 + x]; }
    int cc = x - 3 + t;
    if (cc >= 0 && cc <= 128) { int ss = (cc == 128) ? 126 : cc; s2 += op[y * 128 + ss]; }
  }
  out[idx] = 0.125f * (s1 + s2) + loc[idx];
}

// ---------------- depthwise 8x8 conv (pad_out + pad3, zero) + BN ----------------
__global__ __launch_bounds__(256)
void dw_k(const float* __restrict__ in, const float* __restrict__ w,
          const float* __restrict__ g, const float* __restrict__ bb, float* __restrict__ out)
{
  __shared__ float t[23 * 23];
  const int tid = threadIdx.x;
  const int tx = tid & 15, ty = tid >> 4;
  const int x0 = blockIdx.x * 16, y0 = blockIdx.y * 16;
  const int pc = blockIdx.z;
  const int c = pc & 63;
  const float* ip = in + (size_t)pc * 16384;
  for (int e = tid; e < 529; e += 256) {
    int yy = e / 23, xx = e % 23;
    int iy = y0 + yy - 3, ix = x0 + xx - 3;
    t[e] = (iy >= 0 && iy < 128 && ix >= 0 && ix < 128) ? ip[iy * 128 + ix] : 0.f;
  }
  __syncthreads();
  const float* wk = w + c * 64;
  float s = 0.f;
#pragma unroll
  for (int ky = 0; ky < 8; ++ky)
#pragma unroll
    for (int kx = 0; kx < 8; ++kx)
      s += t[(ty + ky) * 23 + tx + kx] * wk[ky * 8 + kx];
  out[(size_t)pc * 16384 + (y0 + ty) * 128 + x0 + tx] = s * (g[c] * BN_SC) + bb[c];
}

// ---------------- final 1x1 conv (w_pw, no bias) ----------------
__global__ __launch_bounds__(256)
void pw_k(const float* __restrict__ in, const float* __restrict__ w, float* __restrict__ out)
{
  int idx = blockIdx.x * 256 + threadIdx.x;
  int b = idx >> 14, px = idx & 16383;
  const float* ip = in + ((size_t)b << 20) + px;
  float v[64];
#pragma unroll
  for (int i = 0; i < 64; ++i) v[i] = ip[(size_t)i << 14];
  float* op = out + ((size_t)b << 20) + px;
  for (int co = 0; co < 64; ++co) {
    const float* wk = w + co * 64;
    float s = 0.f;
#pragma unroll
    for (int i = 0; i < 64; ++i) s += v[i] * wk[i];
    op[(size_t)co << 14] = s;
  }
}

// =======================================================================
extern "C" void kernel_launch(void* const* d_in, const int* in_sizes, int n_in,
                              void* d_out, int out_size, void* d_ws, size_t ws_size,
                              hipStream_t stream)
{
  const float* x      = (const float*)d_in[0];
  const float* w_qkv  = (const float*)d_in[1];
  const float* w_l1   = (const float*)d_in[2];
  const float* g_l1   = (const float*)d_in[3];
  const float* b_l1   = (const float*)d_in[4];
  const float* w_l2   = (const float*)d_in[5];
  const float* g_l2   = (const float*)d_in[6];
  const float* b_l2   = (const float*)d_in[7];
  const float* f_cos  = (const float*)d_in[8];
  const float* f_sin  = (const float*)d_in[9];
  const float* gb_b1  = (const float*)d_in[10];
  const float* gb_b2  = (const float*)d_in[11];
  const float* gb_w   = (const float*)d_in[12];
  const float* w_post = (const float*)d_in[13];
  const float* g_post = (const float*)d_in[14];
  const float* b_post = (const float*)d_in[15];
  const float* w_gc   = (const float*)d_in[16];
  const float* b_gc   = (const float*)d_in[17];
  const float* w_gc1  = (const float*)d_in[18];
  const float* b_gc1  = (const float*)d_in[19];
  const float* w_gc2  = (const float*)d_in[20];
  const float* b_gc2  = (const float*)d_in[21];
  const float* rpb    = (const float*)d_in[22];
  const float* w_dw   = (const float*)d_in[23];
  const float* g_proj = (const float*)d_in[24];
  const float* b_proj = (const float*)d_in[25];
  const float* w_pw   = (const float*)d_in[26];
  const int*   relidx = (const int*)d_in[27];
  float* out = (float*)d_out;

  // Workspace: max byte used = 102,238,208 (round-2-proven footprint).
  char* ws = (char*)d_ws;
  float* R1   = (float*)(ws + 0);                       // 32 MiB
  float* R2   = (float*)(ws + 33554432);                // 32 MiB
  float* R3   = (float*)(ws + 67108864);                // convgc out / out0
  float* C1   = R3;                                     // 16,515,072 B complex (FFT)
  float* C2   = (float*)(ws + 83623936);                // 16,515,072 B (ends 100,139,008)
  float* XC5  = (float*)(ws + 100139008);               // 1,968,128 B (steps 8-9)
  float* RPBT = (float*)(ws + 102107136);               // 131,072 B (ends 102,238,208)
  float* W1S  = (float*)(ws + 67108864);                // prep weights (dead before FFT)
  float* W2S  = (float*)(ws + 67108864 + 147456);
  float* BLS  = (float*)(ws + 67108864 + 163840);

  // 1. fold BN into local-branch weights + rpb gather
  prep_k<<<144, 256, 0, stream>>>(w_l1, g_l1, b_l1, w_l2, g_l2, b_l2, W1S, W2S, BLS);
  rpbprep_k<<<128, 256, 0, stream>>>(rpb, relidx, RPBT);
  // 2. local_pre = bn(conv1x1) + bn(conv3x3)  -> R1
  conv3x3f_k<M_LOCAL, 128, 128, 1><<<dim3(64, 8, 4), 256, 0, stream>>>(x, W1S, W2S, BLS, nullptr, R1);
  // 3. gabor conv (valid, cos||sin + biases)  -> R2 (xc0, 126x126)
  conv3x3f_k<M_GABOR, 128, 126, 0><<<dim3(64, 8, 4), 256, 0, stream>>>(R1, f_cos, f_sin, gb_b1, gb_b2, R2);
  // 4. fft_h + fw-mix, 2 chunks of 256 planes -> R1 (xc1)
  for (int chunk = 0; chunk < 2; ++chunk) {
    int pb = chunk * 256;
    dft_rows_fwd_k<<<256 * 126, 64, 0, stream>>>(R2, C1, pb);
    dft_cols_fwd_mask_k<<<512, 256, 0, stream>>>(C1, C2);
    dft_cols_inv_k<<<512, 256, 0, stream>>>(C2, C1);
    dft_rows_inv_mix_k<<<256 * 126, 128, 0, stream>>>(C1, R2, gb_w, R1, pb);
  }
  // 5. relu6(bn(conv3x3 w_post)) -> R2 (xc2)
  conv3x3f_k<M_BNRELU6, 126, 126, 1><<<dim3(64, 8, 4), 256, 0, stream>>>(R1, w_post, nullptr, g_post, b_post, R2);
  // 6. maxpool 2x2 s1 -> R1 (125^2)
  mp1_k<<<31250, 256, 0, stream>>>(R2, R1);
  // 7. relu(conv3x3 s2 w_gc) -> R3 (62^2)
  convgc_k<<<7688, 256, 0, stream>>>(R1, w_gc, b_gc, R3);
  // 8. maxpool 2x2 s2 -> XC5 (31^2)
  mp2_k<<<1922, 256, 0, stream>>>(R3, XC5);
  // 9. bilinear resize 31 -> 128 -> R1 (xc6)
  resize_k<<<32768, 256, 0, stream>>>(XC5, R1);
  // 10. relu(conv3x3 w_gc1 + b) -> R2 (xc7)
  conv3x3f_k<M_BIASRELU, 128, 128, 1><<<dim3(64, 8, 4), 256, 0, stream>>>(R1, w_gc1, nullptr, b_gc1, nullptr, R2);
  // 11. 1x1 conv w_gc2 + log_softmax -> R1 (local)
  pwlsm_k<<<512, 256, 0, stream>>>(R2, w_gc2, b_gc2, R1);
  // 12. window attention -> R2 (o)
  attn_k<<<2048, 256, 0, stream>>>(x, w_qkv, RPBT, R2);
  // 13. ox + oy + local -> R3 (out0)
  avgadd_k<<<32768, 256, 0, stream>>>(R2, R1, R3);
  // 14. depthwise 8x8 + bn -> R2
  dw_k<<<dim3(8, 8, 512), 256, 0, stream>>>(R3, w_dw, g_proj, b_proj, R2);
  // 15. 1x1 conv w_pw -> d_out
  pw_k<<<512, 256, 0, stream>>>(R2, w_pw, out);
  (void)in_sizes; (void)n_in; (void)out_size; (void)ws_size;
}

// Round 7
// 2235.402 us; speedup vs baseline: 1.9210x; 1.2918x over previous
//
#include <hip/hip_runtime.h>
#include <math.h>

#define BN_SC 0.9999950000375f
#define P2N   (6.283185307179586f / 126.f)
#define ATT_SCALE 0.35355339059327373f

typedef float v4f __attribute__((ext_vector_type(4)));

enum { M_LOCAL = 0, M_GABOR = 1, M_BNRELU6 = 2, M_BIASRELU = 3 };

// ---------------- weight prep: fold BN scale into w_l1 / w_l2 ----------------
__global__ __launch_bounds__(256) void prep_k(
    const float* __restrict__ w_l1, const float* __restrict__ g_l1, const float* __restrict__ b_l1,
    const float* __restrict__ w_l2, const float* __restrict__ g_l2, const float* __restrict__ b_l2,
    float* __restrict__ w1s, float* __restrict__ w2s, float* __restrict__ bs)
{
  int i = blockIdx.x * 256 + threadIdx.x;
  if (i < 36864) w1s[i] = w_l1[i] * (g_l1[i / 576] * BN_SC);
  if (i < 4096)  w2s[i] = w_l2[i] * (g_l2[i / 64] * BN_SC);
  if (i < 64)    bs[i]  = b_l1[i] + b_l2[i];
}

// ------------- rpb bias pre-gather: rpbt[h][j*64+i] = rpb[relidx[i*64+j]*8+h] -------------
__global__ __launch_bounds__(256) void rpbprep_k(
    const float* __restrict__ rpb, const int* __restrict__ relidx, float* __restrict__ rpbt)
{
  int idx = blockIdx.x * 256 + threadIdx.x; // 32768
  int h = idx >> 12, r = idx & 4095, j = r >> 6, i = r & 63;
  rpbt[idx] = rpb[relidx[i * 64 + j] * 8 + h];
}

// -------- fp32 register-tiled direct conv3x3 (+fused 1x1 for LOCAL), 64->64 ch --------
// block 256 thr: tx[0,8) x 4px, ty[0,8) x 2px, tc[0,4) x 4cout -> tile 32x16 px, 16 couts.
// grid (32, B, 4). Weights staged once to LDS as [cin][tap][co16] (broadcast v4f reads);
// activations staged in 4-cin chunks, pitch 37. Per cin/thread: 24 b32 + 9 b128 LDS vs 288 FMA.
template<int MODE, int IN_HW, int OUT_HW, int PAD>
__global__ __launch_bounds__(256)
void conv3x3r_k(const float* __restrict__ in, const float* __restrict__ wa,
                const float* __restrict__ wb, const float* __restrict__ pa,
                const float* __restrict__ pb, float* __restrict__ out)
{
  __shared__ float wsm[64 * 9 * 16];        // [cin][tap][co16]  36.9 KB
  __shared__ float w11[64 * 16];            // [cin][co16] (LOCAL 1x1)  4 KB
  __shared__ float tile[4 * 18 * 37];       // 4 cin x 18 rows x pitch 37  10.7 KB
  const int tid = threadIdx.x;
  const int tx = tid & 7, ty = (tid >> 3) & 7, tc = tid >> 6;
  const int bx = blockIdx.x & 3, by = blockIdx.x >> 2;   // 4 x-tiles, 8 y-tiles
  const int b = blockIdx.y, cg = blockIdx.z;
  const int x0 = bx * 32, y0 = by * 16;
  const int ix0 = x0 - PAD, iy0 = y0 - PAD;
  const float* inb = in + (size_t)b * 64 * IN_HW * IN_HW;

  // ---- stage weights once: wsm[(cin*9+o)*16+co] ----
  for (int e = tid; e < 9216; e += 256) {
    int co = e & 15, q = e >> 4;
    int o = q % 9, cin = q / 9;
    int c = cg * 16 + co;
    float v;
    if (MODE == M_GABOR)
      v = (c < 32) ? wa[((size_t)c * 64 + cin) * 9 + o]
                   : wb[((size_t)(c - 32) * 64 + cin) * 9 + o];
    else
      v = wa[((size_t)c * 64 + cin) * 9 + o];
    wsm[(cin * 9 + o) * 16 + co] = v;
  }
  if (MODE == M_LOCAL) {
    for (int e = tid; e < 1024; e += 256) {
      int co = e & 15, cin = e >> 4;
      w11[cin * 16 + co] = wb[(size_t)(cg * 16 + co) * 64 + cin];
    }
  }

  float acc[4][2][4];
#pragma unroll
  for (int a = 0; a < 4; ++a)
#pragma unroll
    for (int py = 0; py < 2; ++py)
#pragma unroll
      for (int px = 0; px < 4; ++px) acc[a][py][px] = 0.f;

  const int yb = ty * 2, xb = tx * 4;

  for (int cc = 0; cc < 64; cc += 4) {
    __syncthreads();
    for (int e = tid; e < 4 * 18 * 34; e += 256) {
      int ci = e / 612, r = e - ci * 612;
      int row = r / 34, col = r - row * 34;
      int iy = iy0 + row, ix = ix0 + col;
      float v = 0.f;
      if ((unsigned)iy < (unsigned)IN_HW && (unsigned)ix < (unsigned)IN_HW)
        v = inb[((size_t)(cc + ci) * IN_HW + iy) * IN_HW + ix];
      tile[ci * 666 + row * 37 + col] = v;
    }
    __syncthreads();
#pragma unroll
    for (int ci = 0; ci < 4; ++ci) {
      float p[4][6];
#pragma unroll
      for (int r = 0; r < 4; ++r)
#pragma unroll
        for (int c2 = 0; c2 < 6; ++c2)
          p[r][c2] = tile[ci * 666 + (yb + r) * 37 + xb + c2];
      const int cin = cc + ci;
      v4f wv[9];
#pragma unroll
      for (int o = 0; o < 9; ++o)
        wv[o] = *(const v4f*)&wsm[(cin * 9 + o) * 16 + tc * 4];
#pragma unroll
      for (int dy = 0; dy < 3; ++dy)
#pragma unroll
        for (int dx = 0; dx < 3; ++dx) {
          v4f w = wv[dy * 3 + dx];
#pragma unroll
          for (int a = 0; a < 4; ++a) {
            float wc = w[a];
#pragma unroll
            for (int py = 0; py < 2; ++py)
#pragma unroll
              for (int px = 0; px < 4; ++px)
                acc[a][py][px] += p[py + dy][px + dx] * wc;
          }
        }
      if (MODE == M_LOCAL) {
        v4f w1 = *(const v4f*)&w11[cin * 16 + tc * 4];
#pragma unroll
        for (int a = 0; a < 4; ++a) {
          float wc = w1[a];
#pragma unroll
          for (int py = 0; py < 2; ++py)
#pragma unroll
            for (int px = 0; px < 4; ++px)
              acc[a][py][px] += p[py + 1][px + 1] * wc;
        }
      }
    }
  }

  // ---- epilogue ----
#pragma unroll
  for (int a = 0; a < 4; ++a) {
    const int c = cg * 16 + tc * 4 + a;
    float scale = 1.f, bias;
    if (MODE == M_LOCAL)        { bias = pa[c]; }
    else if (MODE == M_GABOR)   { bias = (c < 32) ? pa[c] : pb[c - 32]; }
    else if (MODE == M_BNRELU6) { scale = pa[c] * BN_SC; bias = pb[c]; }
    else                        { bias = pa[c]; }
#pragma unroll
    for (int py = 0; py < 2; ++py) {
      int oy = y0 + yb + py;
      if (oy >= OUT_HW) continue;
      float* op = out + (((size_t)b * 64 + c) * OUT_HW + oy) * OUT_HW;
      int ox0 = x0 + xb;
#pragma unroll
      for (int px = 0; px < 4; ++px) {
        if (ox0 + px >= OUT_HW) continue;
        float r = acc[a][py][px] * scale + bias;
        if (MODE == M_BNRELU6) r = fminf(fmaxf(r, 0.f), 6.f);
        if (MODE == M_BIASRELU) r = fmaxf(r, 0.f);
        op[ox0 + px] = r;
      }
    }
  }
}

// ======================= DFT (126-pt), table-based, Hermitian-half =======================

__global__ __launch_bounds__(64)
void dft_rows_fwd_k(const float* __restrict__ in, float* __restrict__ outC, int planeBase)
{
  __shared__ float2 r2[63];
  __shared__ float2 T[126];
  const int lp = blockIdx.x / 126, n1 = blockIdx.x % 126;
  const int tid = threadIdx.x;
  const float2* row = (const float2*)(in + (size_t)(planeBase + lp) * 15876 + (size_t)n1 * 126);
  if (tid < 63) r2[tid] = row[tid];
  for (int e = tid; e < 126; e += 64) { float s, c; sincosf(P2N * (float)e, &s, &c); T[e] = make_float2(c, s); }
  __syncthreads();
  const int k2 = tid;
  const int inc = (2 * k2) % 126;
  int m = 0;
  float Er = 0.f, Ei = 0.f, Or = 0.f, Oi = 0.f;
  for (int n = 0; n < 63; ++n) {
    float2 rv = r2[n];
    float2 t = T[m];
    Er += rv.x * t.x; Ei -= rv.x * t.y;
    Or += rv.y * t.x; Oi -= rv.y * t.y;
    m += inc; if (m >= 126) m -= 126;
  }
  float c = T[k2].x, s = T[k2].y;
  float2* o = (float2*)(outC + (size_t)lp * 16128 + (size_t)n1 * 128);
  o[k2] = make_float2(Er + c * Or + s * Oi, Ei + c * Oi - s * Or);
}

__global__ __launch_bounds__(256)
void dft_cols_fwd_mask_k(const float* __restrict__ inC, float* __restrict__ outC)
{
  __shared__ float2 S[4032];
  __shared__ float2 T[126];
  const int lp = blockIdx.x >> 1, gbase = (blockIdx.x & 1) * 32;
  const int tid = threadIdx.x;
  if (tid < 126) { float s, c; sincosf(P2N * (float)tid, &s, &c); T[tid] = make_float2(c, s); }
  const float2* src = (const float2*)(inC + (size_t)lp * 16128);
  for (int e = tid; e < 4032; e += 256) {
    int n1 = e >> 5, c = e & 31;
    S[e] = src[n1 * 64 + gbase + c];
  }
  __syncthreads();
  float2* dst = (float2*)(outC + (size_t)lp * 16128);
  for (int e = tid; e < 2016; e += 256) {
    int k1 = e >> 5, c = e & 31;
    int k2 = gbase + c;
    int inc = 2 * k1;
    int me = 0, mo = k1;
    float Er = 0.f, Ei = 0.f, Or = 0.f, Oi = 0.f;
    for (int u = 0; u < 63; ++u) {
      float2 s0 = S[(2 * u) * 32 + c];
      float2 t0 = T[me];
      Er += s0.x * t0.x + s0.y * t0.y;
      Ei += s0.y * t0.x - s0.x * t0.y;
      float2 s1 = S[(2 * u + 1) * 32 + c];
      float2 t1 = T[mo];
      Or += s1.x * t1.x + s1.y * t1.y;
      Oi += s1.y * t1.x - s1.x * t1.y;
      me += inc; if (me >= 126) me -= 126;
      mo += inc; if (mo >= 126) mo -= 126;
    }
    int f2 = (k2 <= 62) ? k2 : k2 - 126;
    float ar = Er + Or, ai = Ei + Oi;
    float br = Er - Or, bi = Ei - Oi;
    float sa = (k1 * k1 + f2 * f2 > 1600) ? sqrtf(ar * ar + ai * ai) * (1.f / 15876.f) : 0.f;
    int f1b = k1 - 63;
    float sb = (f1b * f1b + f2 * f2 > 1600) ? sqrtf(br * br + bi * bi) * (1.f / 15876.f) : 0.f;
    dst[(size_t)k1 * 64 + k2]        = make_float2(ar * sa, ai * sa);
    dst[(size_t)(k1 + 63) * 64 + k2] = make_float2(br * sb, bi * sb);
  }
}

__global__ __launch_bounds__(256)
void dft_cols_inv_k(const float* __restrict__ inC, float* __restrict__ outC)
{
  __shared__ float2 S[4032];
  __shared__ float2 T[126];
  const int lp = blockIdx.x >> 1, gbase = (blockIdx.x & 1) * 32;
  const int tid = threadIdx.x;
  if (tid < 126) { float s, c; sincosf(P2N * (float)tid, &s, &c); T[tid] = make_float2(c, s); }
  const float2* src = (const float2*)(inC + (size_t)lp * 16128);
  for (int e = tid; e < 4032; e += 256) {
    int k1 = e >> 5, c = e & 31;
    S[e] = src[k1 * 64 + gbase + c];
  }
  __syncthreads();
  float2* dst = (float2*)(outC + (size_t)lp * 16128);
  for (int e = tid; e < 2016; e += 256) {
    int n1 = e >> 5, c = e & 31;
    int k2 = gbase + c;
    int inc = (2 * n1) % 126;
    int me = 0, mo = n1;
    float Er = 0.f, Ei = 0.f, Or = 0.f, Oi = 0.f;
    for (int u = 0; u < 63; ++u) {
      float2 s0 = S[(2 * u) * 32 + c];
      float2 t0 = T[me];
      Er += s0.x * t0.x - s0.y * t0.y;
      Ei += s0.x * t0.y + s0.y * t0.x;
      float2 s1 = S[(2 * u + 1) * 32 + c];
      float2 t1 = T[mo];
      Or += s1.x * t1.x - s1.y * t1.y;
      Oi += s1.x * t1.y + s1.y * t1.x;
      me += inc; if (me >= 126) me -= 126;
      mo += inc; if (mo >= 126) mo -= 126;
    }
    dst[(size_t)n1 * 64 + k2]        = make_float2(Er + Or, Ei + Oi);
    dst[(size_t)(n1 + 63) * 64 + k2] = make_float2(Er - Or, Ei - Oi);
  }
}

__global__ __launch_bounds__(128)
void dft_rows_inv_mix_k(const float* __restrict__ inC, const float* __restrict__ xc0,
                        const float* __restrict__ gb_w, float* __restrict__ out, int planeBase)
{
  __shared__ float2 Z[64];
  __shared__ float2 T[126];
  const int lp = blockIdx.x / 126, n1 = blockIdx.x % 126;
  const int tid = threadIdx.x;
  const float2* src = (const float2*)(inC + (size_t)lp * 16128 + (size_t)n1 * 128);
  if (tid < 64) Z[tid] = src[tid];
  if (tid < 126) { float s, c; sincosf(P2N * (float)tid, &s, &c); T[tid] = make_float2(c, s); }
  __syncthreads();
  const int n2 = tid;
  if (n2 < 126) {
    float a = Z[0].x + ((n2 & 1) ? -Z[63].x : Z[63].x);
    float acc = 0.f;
    int m = n2;
    for (int k2 = 1; k2 < 63; ++k2) {
      float2 z = Z[k2];
      float2 t = T[m];
      acc += z.x * t.x - z.y * t.y;
      m += n2; if (m >= 126) m -= 126;
    }
    a += 2.f * acc;
    float w0 = fmaxf(gb_w[0], 0.f), w1 = fmaxf(gb_w[1], 0.f);
    float inv = 1.f / (w0 + w1 + 1e-8f);
    size_t gi = (size_t)(planeBase + lp) * 15876 + (size_t)n1 * 126 + n2;
    out[gi] = (w0 * inv) * fabsf(a) + (w1 * inv) * xc0[gi];
  }
}

// ---------------- maxpool 2x2 stride1: 126 -> 125 ----------------
__global__ __launch_bounds__(256) void mp1_k(const float* __restrict__ in, float* __restrict__ out)
{
  int idx = blockIdx.x * 256 + threadIdx.x;
  if (idx >= 512 * 125 * 125) return;
  int x = idx % 125, y = (idx / 125) % 125, p = idx / 15625;
  const float* ip = in + (size_t)p * 15876 + (size_t)y * 126 + x;
  out[idx] = fmaxf(fmaxf(ip[0], ip[1]), fmaxf(ip[126], ip[127]));
}

// ---------------- conv3x3 stride2, valid: 125 -> 62, + bias + relu ----------------
__global__ __launch_bounds__(256)
void convgc_k(const float* __restrict__ in, const float* __restrict__ w,
              const float* __restrict__ bias, float* __restrict__ out)
{
  int idx = blockIdx.x * 256 + threadIdx.x;
  if (idx >= 8 * 64 * 62 * 62) return;
  int x = idx % 62, y = (idx / 62) % 62;
  int co = (idx / 3844) % 64, b = idx / 246016;
  float s = bias[co];
  for (int cin = 0; cin < 64; ++cin) {
    const float* ip = in + ((size_t)(b * 64 + cin) * 125 + 2 * y) * 125 + 2 * x;
    const float* wk = w + ((size_t)co * 64 + cin) * 9;
    s += ip[0]   * wk[0] + ip[1]   * wk[1] + ip[2]   * wk[2]
       + ip[125] * wk[3] + ip[126] * wk[4] + ip[127] * wk[5]
       + ip[250] * wk[6] + ip[251] * wk[7] + ip[252] * wk[8];
  }
  out[idx] = fmaxf(s, 0.f);
}

// ---------------- maxpool 2x2 stride2: 62 -> 31 ----------------
__global__ __launch_bounds__(256) void mp2_k(const float* __restrict__ in, float* __restrict__ out)
{
  int idx = blockIdx.x * 256 + threadIdx.x;
  if (idx >= 512 * 31 * 31) return;
  int x = idx % 31, y = (idx / 31) % 31, p = idx / 961;
  const float* ip = in + (size_t)p * 3844 + (size_t)(2 * y) * 62 + 2 * x;
  out[idx] = fmaxf(fmaxf(ip[0], ip[1]), fmaxf(ip[62], ip[63]));
}

// ---------------- bilinear resize 31 -> 128 ----------------
__global__ __launch_bounds__(256) void resize_k(const float* __restrict__ in, float* __restrict__ out)
{
  int idx = blockIdx.x * 256 + threadIdx.x;
  if (idx >= 512 * 128 * 128) return;
  int x = idx & 127, y = (idx >> 7) & 127, p = idx >> 14;
  float sy = (y + 0.5f) * (31.f / 128.f) - 0.5f; sy = fminf(fmaxf(sy, 0.f), 30.f);
  float sx = (x + 0.5f) * (31.f / 128.f) - 0.5f; sx = fminf(fmaxf(sx, 0.f), 30.f);
  int y0 = (int)sy; float fy = sy - (float)y0; int y1 = min(y0 + 1, 30);
  int x0 = (int)sx; float fx = sx - (float)x0; int x1 = min(x0 + 1, 30);
  const float* ip = in + (size_t)p * 961;
  float v = (1.f - fy) * ((1.f - fx) * ip[y0 * 31 + x0] + fx * ip[y0 * 31 + x1])
          + fy         * ((1.f - fx) * ip[y1 * 31 + x0] + fx * ip[y1 * 31 + x1]);
  out[idx] = v;
}

// ---------------- 1x1 conv (w_gc2 + bias) + log_softmax over 64 channels ----------------
__global__ __launch_bounds__(256)
void pwlsm_k(const float* __restrict__ in, const float* __restrict__ w,
             const float* __restrict__ bias, float* __restrict__ out)
{
  __shared__ float zs[64 * 256];
  int idx = blockIdx.x * 256 + threadIdx.x;
  int b = idx >> 14, px = idx & 16383;
  const float* ip = in + ((size_t)b << 20) + px;
  float v[64];
#pragma unroll
  for (int i = 0; i < 64; ++i) v[i] = ip[(size_t)i << 14];
  float m = -1e30f;
  for (int co = 0; co < 64; ++co) {
    float s = bias[co];
    const float* wk = w + co * 64;
#pragma unroll
    for (int i = 0; i < 64; ++i) s += v[i] * wk[i];
    zs[co * 256 + threadIdx.x] = s;
    m = fmaxf(m, s);
  }
  float sum = 0.f;
  for (int co = 0; co < 64; ++co) sum += __expf(zs[co * 256 + threadIdx.x] - m);
  float lse = m + __logf(sum);
  float* op = out + ((size_t)b << 20) + px;
  for (int co = 0; co < 64; ++co) op[(size_t)co << 14] = zs[co * 256 + threadIdx.x] - lse;
}

// ---------------- windowed attention, conflict-free layouts, per-head qkv ----------------
__global__ __launch_bounds__(256)
void attn_k(const float* __restrict__ x, const float* __restrict__ wqkv,
            const float* __restrict__ rpbt, float* __restrict__ o_out)
{
  __shared__ float xt[4096];
  __shared__ float qs[512], ks[512], vs[512];
  __shared__ float P[4096];
  __shared__ float invr[64];
  const int tid = threadIdx.x;
  const int b = blockIdx.x >> 8, gy = (blockIdx.x >> 4) & 15, gx = blockIdx.x & 15;
  const int y0 = gy * 8, x0 = gx * 8;
  const int i = tid & 63, g = tid >> 6;

  for (int e = tid; e < 4096; e += 256) {
    int cin = e >> 6, pix = e & 63;
    xt[e] = x[((size_t)(b * 64 + cin) * 128 + (y0 + (pix >> 3))) * 128 + x0 + (pix & 7)];
  }
  __syncthreads();

  for (int h = 0; h < 8; ++h) {
    const float* rowp[6];
#pragma unroll
    for (int r = 0; r < 6; ++r) {
      int ch24 = g + r * 4;
      int comp = ch24 >> 3, d = ch24 & 7;
      rowp[r] = wqkv + (size_t)(comp * 64 + h * 8 + d) * 64;
    }
    float acc[6];
#pragma unroll
    for (int r = 0; r < 6; ++r) acc[r] = 0.f;
    for (int cb = 0; cb < 64; cb += 4) {
      float xv0 = xt[(cb + 0) * 64 + i];
      float xv1 = xt[(cb + 1) * 64 + i];
      float xv2 = xt[(cb + 2) * 64 + i];
      float xv3 = xt[(cb + 3) * 64 + i];
#pragma unroll
      for (int r = 0; r < 6; ++r) {
        float4 w = *(const float4*)(rowp[r] + cb);
        acc[r] += xv0 * w.x + xv1 * w.y + xv2 * w.z + xv3 * w.w;
      }
    }
#pragma unroll
    for (int r = 0; r < 6; ++r) {
      int ch24 = g + r * 4;
      int comp = ch24 >> 3, d = ch24 & 7;
      float* dst = (comp == 0) ? qs : (comp == 1) ? ks : vs;
      dst[d * 64 + i] = acc[r];
    }
    __syncthreads();
    float qv[8];
#pragma unroll
    for (int d = 0; d < 8; ++d) qv[d] = qs[d * 64 + i];
    const float* rb = rpbt + h * 4096;
    for (int jj = 0; jj < 16; ++jj) {
      int j = g + jj * 4;
      float s = 0.f;
#pragma unroll
      for (int d = 0; d < 8; ++d) s += qv[d] * ks[d * 64 + j];
      P[j * 64 + i] = s * ATT_SCALE + rb[j * 64 + i];
    }
    __syncthreads();
    if (tid < 64) {
      float m = -1e30f;
      for (int j = 0; j < 64; ++j) m = fmaxf(m, P[j * 64 + tid]);
      float sum = 0.f;
      for (int j = 0; j < 64; ++j) { float p = __expf(P[j * 64 + tid] - m); P[j * 64 + tid] = p; sum += p; }
      invr[tid] = 1.f / sum;
    }
    __syncthreads();
    {
      float s0 = 0.f, s1 = 0.f;
      for (int j = 0; j < 64; ++j) {
        float p = P[j * 64 + i];
        s0 += p * vs[g * 64 + j];
        s1 += p * vs[(g + 4) * 64 + j];
      }
      float inv = invr[i];
      int row = y0 + (i >> 3), col = x0 + (i & 7);
      o_out[((size_t)(b * 64 + h * 8 + g) * 128 + row) * 128 + col] = s0 * inv;
      o_out[((size_t)(b * 64 + h * 8 + g + 4) * 128 + row) * 128 + col] = s1 * inv;
    }
    __syncthreads();
  }
}

// ------- directional avg pools (reflect+zero pad semantics) + add local -------
__global__ __launch_bounds__(256)
void avgadd_k(const float* __restrict__ o, const float* __restrict__ loc, float* __restrict__ out)
{
  int idx = blockIdx.x * 256 + threadIdx.x;
  if (idx >= 8388608) return;
  int x = idx & 127, y = (idx >> 7) & 127;
  size_t p = (size_t)(idx >> 14);
  const float* op = o + (p << 14);
  float s1 = 0.f, s2 = 0.f;
#pragma unroll
  for (int t = 0; t < 8; ++t) {
    int r = y - 3 + t;
    if (r >= 0 && r <= 128) { int rr = (r == 128) ? 126 : r; s1 += op[rr * 128 + x]; }
    int cc = x - 3 + t;
    if (cc >= 0 && cc <= 128) { int ss = (cc == 128) ? 126 : cc; s2 += op[y * 128 + ss]; }
  }
  out[idx] = 0.125f * (s1 + s2) + loc[idx];
}

// ---------------- depthwise 8x8 conv (pad_out + pad3, zero) + BN ----------------
__global__ __launch_bounds__(256)
void dw_k(const float* __restrict__ in, const float* __restrict__ w,
          const float* __restrict__ g, const float* __restrict__ bb, float* __restrict__ out)
{
  __shared__ float t[23 * 23];
  const int tid = threadIdx.x;
  const int tx = tid & 15, ty = tid >> 4;
  const int x0 = blockIdx.x * 16, y0 = blockIdx.y * 16;
  const int pc = blockIdx.z;
  const int c = pc & 63;
  const float* ip = in + (size_t)pc * 16384;
  for (int e = tid; e < 529; e += 256) {
    int yy = e / 23, xx = e % 23;
    int iy = y0 + yy - 3, ix = x0 + xx - 3;
    t[e] = (iy >= 0 && iy < 128 && ix >= 0 && ix < 128) ? ip[iy * 128 + ix] : 0.f;
  }
  __syncthreads();
  const float* wk = w + c * 64;
  float s = 0.f;
#pragma unroll
  for (int ky = 0; ky < 8; ++ky)
#pragma unroll
    for (int kx = 0; kx < 8; ++kx)
      s += t[(ty + ky) * 23 + tx + kx] * wk[ky * 8 + kx];
  out[(size_t)pc * 16384 + (y0 + ty) * 128 + x0 + tx] = s * (g[c] * BN_SC) + bb[c];
}

// ---------------- final 1x1 conv (w_pw, no bias) ----------------
__global__ __launch_bounds__(256)
void pw_k(const float* __restrict__ in, const float* __restrict__ w, float* __restrict__ out)
{
  int idx = blockIdx.x * 256 + threadIdx.x;
  int b = idx >> 14, px = idx & 16383;
  const float* ip = in + ((size_t)b << 20) + px;
  float v[64];
#pragma unroll
  for (int i = 0; i < 64; ++i) v[i] = ip[(size_t)i << 14];
  float* op = out + ((size_t)b << 20) + px;
  for (int co = 0; co < 64; ++co) {
    const float* wk = w + co * 64;
    float s = 0.f;
#pragma unroll
    for (int i = 0; i < 64; ++i) s += v[i] * wk[i];
    op[(size_t)co << 14] = s;
  }
}

// =======================================================================
extern "C" void kernel_launch(void* const* d_in, const int* in_sizes, int n_in,
                              void* d_out, int out_size, void* d_ws, size_t ws_size,
                              hipStream_t stream)
{
  const float* x      = (const float*)d_in[0];
  const float* w_qkv  = (const float*)d_in[1];
  const float* w_l1   = (const float*)d_in[2];
  const float* g_l1   = (const float*)d_in[3];
  const float* b_l1   = (const float*)d_in[4];
  const float* w_l2   = (const float*)d_in[5];
  const float* g_l2   = (const float*)d_in[6];
  const float* b_l2   = (const float*)d_in[7];
  const float* f_cos  = (const float*)d_in[8];
  const float* f_sin  = (const float*)d_in[9];
  const float* gb_b1  = (const float*)d_in[10];
  const float* gb_b2  = (const float*)d_in[11];
  const float* gb_w   = (const float*)d_in[12];
  const float* w_post = (const float*)d_in[13];
  const float* g_post = (const float*)d_in[14];
  const float* b_post = (const float*)d_in[15];
  const float* w_gc   = (const float*)d_in[16];
  const float* b_gc   = (const float*)d_in[17];
  const float* w_gc1  = (const float*)d_in[18];
  const float* b_gc1  = (const float*)d_in[19];
  const float* w_gc2  = (const float*)d_in[20];
  const float* b_gc2  = (const float*)d_in[21];
  const float* rpb    = (const float*)d_in[22];
  const float* w_dw   = (const float*)d_in[23];
  const float* g_proj = (const float*)d_in[24];
  const float* b_proj = (const float*)d_in[25];
  const float* w_pw   = (const float*)d_in[26];
  const int*   relidx = (const int*)d_in[27];
  float* out = (float*)d_out;

  // Workspace: max byte used = 102,238,208 (round-2-proven footprint).
  char* ws = (char*)d_ws;
  float* R1   = (float*)(ws + 0);                       // 32 MiB
  float* R2   = (float*)(ws + 33554432);                // 32 MiB
  float* R3   = (float*)(ws + 67108864);                // convgc out / out0
  float* C1   = R3;                                     // 16,515,072 B complex (FFT)
  float* C2   = (float*)(ws + 83623936);                // 16,515,072 B (ends 100,139,008)
  float* XC5  = (float*)(ws + 100139008);               // 1,968,128 B (steps 8-9)
  float* RPBT = (float*)(ws + 102107136);               // 131,072 B (ends 102,238,208)
  float* W1S  = (float*)(ws + 67108864);                // prep weights (dead before FFT)
  float* W2S  = (float*)(ws + 67108864 + 147456);
  float* BLS  = (float*)(ws + 67108864 + 163840);

  // 1. fold BN into local-branch weights + rpb gather
  prep_k<<<144, 256, 0, stream>>>(w_l1, g_l1, b_l1, w_l2, g_l2, b_l2, W1S, W2S, BLS);
  rpbprep_k<<<128, 256, 0, stream>>>(rpb, relidx, RPBT);
  // 2. local_pre = bn(conv1x1) + bn(conv3x3)  -> R1
  conv3x3r_k<M_LOCAL, 128, 128, 1><<<dim3(32, 8, 4), 256, 0, stream>>>(x, W1S, W2S, BLS, nullptr, R1);
  // 3. gabor conv (valid, cos||sin + biases)  -> R2 (xc0, 126x126)
  conv3x3r_k<M_GABOR, 128, 126, 0><<<dim3(32, 8, 4), 256, 0, stream>>>(R1, f_cos, f_sin, gb_b1, gb_b2, R2);
  // 4. fft_h + fw-mix, 2 chunks of 256 planes -> R1 (xc1)
  for (int chunk = 0; chunk < 2; ++chunk) {
    int pb = chunk * 256;
    dft_rows_fwd_k<<<256 * 126, 64, 0, stream>>>(R2, C1, pb);
    dft_cols_fwd_mask_k<<<512, 256, 0, stream>>>(C1, C2);
    dft_cols_inv_k<<<512, 256, 0, stream>>>(C2, C1);
    dft_rows_inv_mix_k<<<256 * 126, 128, 0, stream>>>(C1, R2, gb_w, R1, pb);
  }
  // 5. relu6(bn(conv3x3 w_post)) -> R2 (xc2)
  conv3x3r_k<M_BNRELU6, 126, 126, 1><<<dim3(32, 8, 4), 256, 0, stream>>>(R1, w_post, nullptr, g_post, b_post, R2);
  // 6. maxpool 2x2 s1 -> R1 (125^2)
  mp1_k<<<31250, 256, 0, stream>>>(R2, R1);
  // 7. relu(conv3x3 s2 w_gc) -> R3 (62^2)
  convgc_k<<<7688, 256, 0, stream>>>(R1, w_gc, b_gc, R3);
  // 8. maxpool 2x2 s2 -> XC5 (31^2)
  mp2_k<<<1922, 256, 0, stream>>>(R3, XC5);
  // 9. bilinear resize 31 -> 128 -> R1 (xc6)
  resize_k<<<32768, 256, 0, stream>>>(XC5, R1);
  // 10. relu(conv3x3 w_gc1 + b) -> R2 (xc7)
  conv3x3r_k<M_BIASRELU, 128, 128, 1><<<dim3(32, 8, 4), 256, 0, stream>>>(R1, w_gc1, nullptr, b_gc1, nullptr, R2);
  // 11. 1x1 conv w_gc2 + log_softmax -> R1 (local)
  pwlsm_k<<<512, 256, 0, stream>>>(R2, w_gc2, b_gc2, R1);
  // 12. window attention -> R2 (o)
  attn_k<<<2048, 256, 0, stream>>>(x, w_qkv, RPBT, R2);
  // 13. ox + oy + local -> R3 (out0)
  avgadd_k<<<32768, 256, 0, stream>>>(R2, R1, R3);
  // 14. depthwise 8x8 + bn -> R2
  dw_k<<<dim3(8, 8, 512), 256, 0, stream>>>(R3, w_dw, g_proj, b_proj, R2);
  // 15. 1x1 conv w_pw -> d_out
  pw_k<<<512, 256, 0, stream>>>(R2, w_pw, out);
  (void)in_sizes; (void)n_in; (void)out_size; (void)ws_size;
}

// Round 8
// 2078.102 us; speedup vs baseline: 2.0664x; 1.0757x over previous
//
#include <hip/hip_runtime.h>
#include <math.h>

#define BN_SC 0.9999950000375f
#define P2N   (6.283185307179586f / 126.f)
#define ATT_SCALE 0.35355339059327373f

typedef float v4f __attribute__((ext_vector_type(4)));

enum { M_LOCAL = 0, M_GABOR = 1, M_BNRELU6 = 2, M_BIASRELU = 3 };

// ---------------- weight prep: fold BN scale into w_l1 / w_l2 ----------------
__global__ __launch_bounds__(256) void prep_k(
    const float* __restrict__ w_l1, const float* __restrict__ g_l1, const float* __restrict__ b_l1,
    const float* __restrict__ w_l2, const float* __restrict__ g_l2, const float* __restrict__ b_l2,
    float* __restrict__ w1s, float* __restrict__ w2s, float* __restrict__ bs)
{
  int i = blockIdx.x * 256 + threadIdx.x;
  if (i < 36864) w1s[i] = w_l1[i] * (g_l1[i / 576] * BN_SC);
  if (i < 4096)  w2s[i] = w_l2[i] * (g_l2[i / 64] * BN_SC);
  if (i < 64)    bs[i]  = b_l1[i] + b_l2[i];
}

// ------------- rpb bias pre-gather: rpbt[h][j*64+i] = rpb[relidx[i*64+j]*8+h] -------------
__global__ __launch_bounds__(256) void rpbprep_k(
    const float* __restrict__ rpb, const int* __restrict__ relidx, float* __restrict__ rpbt)
{
  int idx = blockIdx.x * 256 + threadIdx.x; // 32768
  int h = idx >> 12, r = idx & 4095, j = r >> 6, i = r & 63;
  rpbt[idx] = rpb[relidx[i * 64 + j] * 8 + h];
}

// -------- fp32 register-tiled direct conv3x3 (+fused 1x1 for LOCAL), 64->64 ch --------
template<int MODE, int IN_HW, int OUT_HW, int PAD>
__global__ __launch_bounds__(256)
void conv3x3r_k(const float* __restrict__ in, const float* __restrict__ wa,
                const float* __restrict__ wb, const float* __restrict__ pa,
                const float* __restrict__ pb, float* __restrict__ out)
{
  __shared__ float wsm[64 * 9 * 16];        // [cin][tap][co16]
  __shared__ float w11[64 * 16];            // [cin][co16] (LOCAL 1x1)
  __shared__ float tile[4 * 18 * 37];       // 4 cin x 18 rows x pitch 37
  const int tid = threadIdx.x;
  const int tx = tid & 7, ty = (tid >> 3) & 7, tc = tid >> 6;
  const int bx = blockIdx.x & 3, by = blockIdx.x >> 2;
  const int b = blockIdx.y, cg = blockIdx.z;
  const int x0 = bx * 32, y0 = by * 16;
  const int ix0 = x0 - PAD, iy0 = y0 - PAD;
  const float* inb = in + (size_t)b * 64 * IN_HW * IN_HW;

  for (int e = tid; e < 9216; e += 256) {
    int co = e & 15, q = e >> 4;
    int o = q % 9, cin = q / 9;
    int c = cg * 16 + co;
    float v;
    if (MODE == M_GABOR)
      v = (c < 32) ? wa[((size_t)c * 64 + cin) * 9 + o]
                   : wb[((size_t)(c - 32) * 64 + cin) * 9 + o];
    else
      v = wa[((size_t)c * 64 + cin) * 9 + o];
    wsm[(cin * 9 + o) * 16 + co] = v;
  }
  if (MODE == M_LOCAL) {
    for (int e = tid; e < 1024; e += 256) {
      int co = e & 15, cin = e >> 4;
      w11[cin * 16 + co] = wb[(size_t)(cg * 16 + co) * 64 + cin];
    }
  }

  float acc[4][2][4];
#pragma unroll
  for (int a = 0; a < 4; ++a)
#pragma unroll
    for (int py = 0; py < 2; ++py)
#pragma unroll
      for (int px = 0; px < 4; ++px) acc[a][py][px] = 0.f;

  const int yb = ty * 2, xb = tx * 4;

  for (int cc = 0; cc < 64; cc += 4) {
    __syncthreads();
    for (int e = tid; e < 4 * 18 * 34; e += 256) {
      int ci = e / 612, r = e - ci * 612;
      int row = r / 34, col = r - row * 34;
      int iy = iy0 + row, ix = ix0 + col;
      float v = 0.f;
      if ((unsigned)iy < (unsigned)IN_HW && (unsigned)ix < (unsigned)IN_HW)
        v = inb[((size_t)(cc + ci) * IN_HW + iy) * IN_HW + ix];
      tile[ci * 666 + row * 37 + col] = v;
    }
    __syncthreads();
#pragma unroll
    for (int ci = 0; ci < 4; ++ci) {
      float p[4][6];
#pragma unroll
      for (int r = 0; r < 4; ++r)
#pragma unroll
        for (int c2 = 0; c2 < 6; ++c2)
          p[r][c2] = tile[ci * 666 + (yb + r) * 37 + xb + c2];
      const int cin = cc + ci;
      v4f wv[9];
#pragma unroll
      for (int o = 0; o < 9; ++o)
        wv[o] = *(const v4f*)&wsm[(cin * 9 + o) * 16 + tc * 4];
#pragma unroll
      for (int dy = 0; dy < 3; ++dy)
#pragma unroll
        for (int dx = 0; dx < 3; ++dx) {
          v4f w = wv[dy * 3 + dx];
#pragma unroll
          for (int a = 0; a < 4; ++a) {
            float wc = w[a];
#pragma unroll
            for (int py = 0; py < 2; ++py)
#pragma unroll
              for (int px = 0; px < 4; ++px)
                acc[a][py][px] += p[py + dy][px + dx] * wc;
          }
        }
      if (MODE == M_LOCAL) {
        v4f w1 = *(const v4f*)&w11[cin * 16 + tc * 4];
#pragma unroll
        for (int a = 0; a < 4; ++a) {
          float wc = w1[a];
#pragma unroll
          for (int py = 0; py < 2; ++py)
#pragma unroll
            for (int px = 0; px < 4; ++px)
              acc[a][py][px] += p[py + 1][px + 1] * wc;
        }
      }
    }
  }

#pragma unroll
  for (int a = 0; a < 4; ++a) {
    const int c = cg * 16 + tc * 4 + a;
    float scale = 1.f, bias;
    if (MODE == M_LOCAL)        { bias = pa[c]; }
    else if (MODE == M_GABOR)   { bias = (c < 32) ? pa[c] : pb[c - 32]; }
    else if (MODE == M_BNRELU6) { scale = pa[c] * BN_SC; bias = pb[c]; }
    else                        { bias = pa[c]; }
#pragma unroll
    for (int py = 0; py < 2; ++py) {
      int oy = y0 + yb + py;
      if (oy >= OUT_HW) continue;
      float* op = out + (((size_t)b * 64 + c) * OUT_HW + oy) * OUT_HW;
      int ox0 = x0 + xb;
#pragma unroll
      for (int px = 0; px < 4; ++px) {
        if (ox0 + px >= OUT_HW) continue;
        float r = acc[a][py][px] * scale + bias;
        if (MODE == M_BNRELU6) r = fminf(fmaxf(r, 0.f), 6.f);
        if (MODE == M_BIASRELU) r = fmaxf(r, 0.f);
        op[ox0 + px] = r;
      }
    }
  }
}

// -------- fp32 register-tiled stride-2 conv3x3 valid (125 -> 62), + bias + relu --------
// block 256 thr: tx,ty in [0,8) -> 2x2 output px each (16x16 tile); tc in [0,4) -> 8 couts.
// blockIdx.z in {0,1} selects cout half (32 couts/block). Per 4-cin chunk: stage 33x33
// input patch (pitch 35) + [ci][tap][co32] weights in LDS; 25 b32 + 18 bcast b128 vs 288 FMA.
__global__ __launch_bounds__(256)
void convgc_t(const float* __restrict__ in, const float* __restrict__ w,
              const float* __restrict__ bias, float* __restrict__ out)
{
  __shared__ float tile[4 * 33 * 35];   // 18.5 KB
  __shared__ float wt[4 * 9 * 32];      // 4.6 KB
  const int tid = threadIdx.x;
  const int tx = tid & 7, ty = (tid >> 3) & 7, tc = tid >> 6;
  const int bx = blockIdx.x & 3, by = blockIdx.x >> 2;
  const int b = blockIdx.y, zg = blockIdx.z;          // cout half
  const int x0 = bx * 16, y0 = by * 16;               // output coords
  const float* inb = in + (size_t)b * 64 * 125 * 125;

  float acc[8][2][2];
#pragma unroll
  for (int a = 0; a < 8; ++a)
#pragma unroll
    for (int py = 0; py < 2; ++py)
#pragma unroll
      for (int px = 0; px < 2; ++px) acc[a][py][px] = 0.f;

  for (int cc = 0; cc < 64; cc += 4) {
    __syncthreads();
    // stage input: 4 cin x 33x33 starting at (2*y0, 2*x0)
    for (int e = tid; e < 4 * 33 * 33; e += 256) {
      int ci = e / 1089, r = e - ci * 1089;
      int row = r / 33, col = r - row * 33;
      int iy = 2 * y0 + row, ix = 2 * x0 + col;
      float v = 0.f;
      if (iy < 125 && ix < 125)
        v = inb[((size_t)(cc + ci) * 125 + iy) * 125 + ix];
      tile[ci * 1155 + row * 35 + col] = v;
    }
    // stage weights: wt[(ci*9+o)*32+co], co in this z-half
    for (int e = tid; e < 1152; e += 256) {
      int co = e & 31, q = e >> 5;
      int ci = q / 9, o = q - ci * 9;
      wt[q * 32 + co] = w[((size_t)(zg * 32 + co) * 64 + cc + ci) * 9 + o];
    }
    __syncthreads();
#pragma unroll
    for (int ci = 0; ci < 4; ++ci) {
      float p[5][5];
#pragma unroll
      for (int r = 0; r < 5; ++r)
#pragma unroll
        for (int c2 = 0; c2 < 5; ++c2)
          p[r][c2] = tile[ci * 1155 + (4 * ty + r) * 35 + 4 * tx + c2];
#pragma unroll
      for (int o = 0; o < 9; ++o) {
        const int dy = o / 3, dx = o - dy * 3;
        v4f w0 = *(const v4f*)&wt[(ci * 9 + o) * 32 + tc * 8];
        v4f w1 = *(const v4f*)&wt[(ci * 9 + o) * 32 + tc * 8 + 4];
#pragma unroll
        for (int py = 0; py < 2; ++py)
#pragma unroll
          for (int px = 0; px < 2; ++px) {
            float pv = p[2 * py + dy][2 * px + dx];
#pragma unroll
            for (int a = 0; a < 4; ++a) {
              acc[a][py][px]     += pv * w0[a];
              acc[a + 4][py][px] += pv * w1[a];
            }
          }
      }
    }
  }

#pragma unroll
  for (int a = 0; a < 8; ++a) {
    const int c = zg * 32 + tc * 8 + a;
    const float bv = bias[c];
#pragma unroll
    for (int py = 0; py < 2; ++py) {
      int oy = y0 + ty * 2 + py;
      if (oy >= 62) continue;
      float* op = out + (((size_t)b * 64 + c) * 62 + oy) * 62;
#pragma unroll
      for (int px = 0; px < 2; ++px) {
        int ox = x0 + tx * 2 + px;
        if (ox >= 62) continue;
        op[ox] = fmaxf(acc[a][py][px] + bv, 0.f);
      }
    }
  }
}

// ======================= DFT (126-pt), table-based, Hermitian-half =======================

__global__ __launch_bounds__(64)
void dft_rows_fwd_k(const float* __restrict__ in, float* __restrict__ outC, int planeBase)
{
  __shared__ float2 r2[63];
  __shared__ float2 T[126];
  const int lp = blockIdx.x / 126, n1 = blockIdx.x % 126;
  const int tid = threadIdx.x;
  const float2* row = (const float2*)(in + (size_t)(planeBase + lp) * 15876 + (size_t)n1 * 126);
  if (tid < 63) r2[tid] = row[tid];
  for (int e = tid; e < 126; e += 64) { float s, c; sincosf(P2N * (float)e, &s, &c); T[e] = make_float2(c, s); }
  __syncthreads();
  const int k2 = tid;
  const int inc = (2 * k2) % 126;
  int m = 0;
  float Er = 0.f, Ei = 0.f, Or = 0.f, Oi = 0.f;
  for (int n = 0; n < 63; ++n) {
    float2 rv = r2[n];
    float2 t = T[m];
    Er += rv.x * t.x; Ei -= rv.x * t.y;
    Or += rv.y * t.x; Oi -= rv.y * t.y;
    m += inc; if (m >= 126) m -= 126;
  }
  float c = T[k2].x, s = T[k2].y;
  float2* o = (float2*)(outC + (size_t)lp * 16128 + (size_t)n1 * 128);
  o[k2] = make_float2(Er + c * Or + s * Oi, Ei + c * Oi - s * Or);
}

__global__ __launch_bounds__(256)
void dft_cols_fwd_mask_k(const float* __restrict__ inC, float* __restrict__ outC)
{
  __shared__ float2 S[4032];
  __shared__ float2 T[126];
  const int lp = blockIdx.x >> 1, gbase = (blockIdx.x & 1) * 32;
  const int tid = threadIdx.x;
  if (tid < 126) { float s, c; sincosf(P2N * (float)tid, &s, &c); T[tid] = make_float2(c, s); }
  const float2* src = (const float2*)(inC + (size_t)lp * 16128);
  for (int e = tid; e < 4032; e += 256) {
    int n1 = e >> 5, c = e & 31;
    S[e] = src[n1 * 64 + gbase + c];
  }
  __syncthreads();
  float2* dst = (float2*)(outC + (size_t)lp * 16128);
  for (int e = tid; e < 2016; e += 256) {
    int k1 = e >> 5, c = e & 31;
    int k2 = gbase + c;
    int inc = 2 * k1;
    int me = 0, mo = k1;
    float Er = 0.f, Ei = 0.f, Or = 0.f, Oi = 0.f;
    for (int u = 0; u < 63; ++u) {
      float2 s0 = S[(2 * u) * 32 + c];
      float2 t0 = T[me];
      Er += s0.x * t0.x + s0.y * t0.y;
      Ei += s0.y * t0.x - s0.x * t0.y;
      float2 s1 = S[(2 * u + 1) * 32 + c];
      float2 t1 = T[mo];
      Or += s1.x * t1.x + s1.y * t1.y;
      Oi += s1.y * t1.x - s1.x * t1.y;
      me += inc; if (me >= 126) me -= 126;
      mo += inc; if (mo >= 126) mo -= 126;
    }
    int f2 = (k2 <= 62) ? k2 : k2 - 126;
    float ar = Er + Or, ai = Ei + Oi;
    float br = Er - Or, bi = Ei - Oi;
    float sa = (k1 * k1 + f2 * f2 > 1600) ? sqrtf(ar * ar + ai * ai) * (1.f / 15876.f) : 0.f;
    int f1b = k1 - 63;
    float sb = (f1b * f1b + f2 * f2 > 1600) ? sqrtf(br * br + bi * bi) * (1.f / 15876.f) : 0.f;
    dst[(size_t)k1 * 64 + k2]        = make_float2(ar * sa, ai * sa);
    dst[(size_t)(k1 + 63) * 64 + k2] = make_float2(br * sb, bi * sb);
  }
}

__global__ __launch_bounds__(256)
void dft_cols_inv_k(const float* __restrict__ inC, float* __restrict__ outC)
{
  __shared__ float2 S[4032];
  __shared__ float2 T[126];
  const int lp = blockIdx.x >> 1, gbase = (blockIdx.x & 1) * 32;
  const int tid = threadIdx.x;
  if (tid < 126) { float s, c; sincosf(P2N * (float)tid, &s, &c); T[tid] = make_float2(c, s); }
  const float2* src = (const float2*)(inC + (size_t)lp * 16128);
  for (int e = tid; e < 4032; e += 256) {
    int k1 = e >> 5, c = e & 31;
    S[e] = src[k1 * 64 + gbase + c];
  }
  __syncthreads();
  float2* dst = (float2*)(outC + (size_t)lp * 16128);
  for (int e = tid; e < 2016; e += 256) {
    int n1 = e >> 5, c = e & 31;
    int k2 = gbase + c;
    int inc = (2 * n1) % 126;
    int me = 0, mo = n1;
    float Er = 0.f, Ei = 0.f, Or = 0.f, Oi = 0.f;
    for (int u = 0; u < 63; ++u) {
      float2 s0 = S[(2 * u) * 32 + c];
      float2 t0 = T[me];
      Er += s0.x * t0.x - s0.y * t0.y;
      Ei += s0.x * t0.y + s0.y * t0.x;
      float2 s1 = S[(2 * u + 1) * 32 + c];
      float2 t1 = T[mo];
      Or += s1.x * t1.x - s1.y * t1.y;
      Oi += s1.x * t1.y + s1.y * t1.x;
      me += inc; if (me >= 126) me -= 126;
      mo += inc; if (mo >= 126) mo -= 126;
    }
    dst[(size_t)n1 * 64 + k2]        = make_float2(Er + Or, Ei + Oi);
    dst[(size_t)(n1 + 63) * 64 + k2] = make_float2(Er - Or, Ei - Oi);
  }
}

__global__ __launch_bounds__(128)
void dft_rows_inv_mix_k(const float* __restrict__ inC, const float* __restrict__ xc0,
                        const float* __restrict__ gb_w, float* __restrict__ out, int planeBase)
{
  __shared__ float2 Z[64];
  __shared__ float2 T[126];
  const int lp = blockIdx.x / 126, n1 = blockIdx.x % 126;
  const int tid = threadIdx.x;
  const float2* src = (const float2*)(inC + (size_t)lp * 16128 + (size_t)n1 * 128);
  if (tid < 64) Z[tid] = src[tid];
  if (tid < 126) { float s, c; sincosf(P2N * (float)tid, &s, &c); T[tid] = make_float2(c, s); }
  __syncthreads();
  const int n2 = tid;
  if (n2 < 126) {
    float a = Z[0].x + ((n2 & 1) ? -Z[63].x : Z[63].x);
    float acc = 0.f;
    int m = n2;
    for (int k2 = 1; k2 < 63; ++k2) {
      float2 z = Z[k2];
      float2 t = T[m];
      acc += z.x * t.x - z.y * t.y;
      m += n2; if (m >= 126) m -= 126;
    }
    a += 2.f * acc;
    float w0 = fmaxf(gb_w[0], 0.f), w1 = fmaxf(gb_w[1], 0.f);
    float inv = 1.f / (w0 + w1 + 1e-8f);
    size_t gi = (size_t)(planeBase + lp) * 15876 + (size_t)n1 * 126 + n2;
    out[gi] = (w0 * inv) * fabsf(a) + (w1 * inv) * xc0[gi];
  }
}

// ---------------- maxpool 2x2 stride1: 126 -> 125 ----------------
__global__ __launch_bounds__(256) void mp1_k(const float* __restrict__ in, float* __restrict__ out)
{
  int idx = blockIdx.x * 256 + threadIdx.x;
  if (idx >= 512 * 125 * 125) return;
  int x = idx % 125, y = (idx / 125) % 125, p = idx / 15625;
  const float* ip = in + (size_t)p * 15876 + (size_t)y * 126 + x;
  out[idx] = fmaxf(fmaxf(ip[0], ip[1]), fmaxf(ip[126], ip[127]));
}

// ---------------- maxpool 2x2 stride2: 62 -> 31 ----------------
__global__ __launch_bounds__(256) void mp2_k(const float* __restrict__ in, float* __restrict__ out)
{
  int idx = blockIdx.x * 256 + threadIdx.x;
  if (idx >= 512 * 31 * 31) return;
  int x = idx % 31, y = (idx / 31) % 31, p = idx / 961;
  const float* ip = in + (size_t)p * 3844 + (size_t)(2 * y) * 62 + 2 * x;
  out[idx] = fmaxf(fmaxf(ip[0], ip[1]), fmaxf(ip[62], ip[63]));
}

// ---------------- bilinear resize 31 -> 128 ----------------
__global__ __launch_bounds__(256) void resize_k(const float* __restrict__ in, float* __restrict__ out)
{
  int idx = blockIdx.x * 256 + threadIdx.x;
  if (idx >= 512 * 128 * 128) return;
  int x = idx & 127, y = (idx >> 7) & 127, p = idx >> 14;
  float sy = (y + 0.5f) * (31.f / 128.f) - 0.5f; sy = fminf(fmaxf(sy, 0.f), 30.f);
  float sx = (x + 0.5f) * (31.f / 128.f) - 0.5f; sx = fminf(fmaxf(sx, 0.f), 30.f);
  int y0 = (int)sy; float fy = sy - (float)y0; int y1 = min(y0 + 1, 30);
  int x0 = (int)sx; float fx = sx - (float)x0; int x1 = min(x0 + 1, 30);
  const float* ip = in + (size_t)p * 961;
  float v = (1.f - fy) * ((1.f - fx) * ip[y0 * 31 + x0] + fx * ip[y0 * 31 + x1])
          + fy         * ((1.f - fx) * ip[y1 * 31 + x0] + fx * ip[y1 * 31 + x1]);
  out[idx] = v;
}

// ---------------- 1x1 conv (w_gc2 + bias) + log_softmax over 64 channels ----------------
__global__ __launch_bounds__(256)
void pwlsm_k(const float* __restrict__ in, const float* __restrict__ w,
             const float* __restrict__ bias, float* __restrict__ out)
{
  __shared__ float zs[64 * 256];
  int idx = blockIdx.x * 256 + threadIdx.x;
  int b = idx >> 14, px = idx & 16383;
  const float* ip = in + ((size_t)b << 20) + px;
  float v[64];
#pragma unroll
  for (int i = 0; i < 64; ++i) v[i] = ip[(size_t)i << 14];
  float m = -1e30f;
  for (int co = 0; co < 64; ++co) {
    float s = bias[co];
    const float* wk = w + co * 64;
#pragma unroll
    for (int i = 0; i < 64; ++i) s += v[i] * wk[i];
    zs[co * 256 + threadIdx.x] = s;
    m = fmaxf(m, s);
  }
  float sum = 0.f;
  for (int co = 0; co < 64; ++co) sum += __expf(zs[co * 256 + threadIdx.x] - m);
  float lse = m + __logf(sum);
  float* op = out + ((size_t)b << 20) + px;
  for (int co = 0; co < 64; ++co) op[(size_t)co << 14] = zs[co * 256 + threadIdx.x] - lse;
}

// ---------------- windowed attention, conflict-free layouts, per-head qkv ----------------
__global__ __launch_bounds__(256)
void attn_k(const float* __restrict__ x, const float* __restrict__ wqkv,
            const float* __restrict__ rpbt, float* __restrict__ o_out)
{
  __shared__ float xt[4096];
  __shared__ float qs[512], ks[512], vs[512];
  __shared__ float P[4096];
  __shared__ float invr[64];
  const int tid = threadIdx.x;
  const int b = blockIdx.x >> 8, gy = (blockIdx.x >> 4) & 15, gx = blockIdx.x & 15;
  const int y0 = gy * 8, x0 = gx * 8;
  const int i = tid & 63, g = tid >> 6;

  for (int e = tid; e < 4096; e += 256) {
    int cin = e >> 6, pix = e & 63;
    xt[e] = x[((size_t)(b * 64 + cin) * 128 + (y0 + (pix >> 3))) * 128 + x0 + (pix & 7)];
  }
  __syncthreads();

  for (int h = 0; h < 8; ++h) {
    const float* rowp[6];
#pragma unroll
    for (int r = 0; r < 6; ++r) {
      int ch24 = g + r * 4;
      int comp = ch24 >> 3, d = ch24 & 7;
      rowp[r] = wqkv + (size_t)(comp * 64 + h * 8 + d) * 64;
    }
    float acc[6];
#pragma unroll
    for (int r = 0; r < 6; ++r) acc[r] = 0.f;
    for (int cb = 0; cb < 64; cb += 4) {
      float xv0 = xt[(cb + 0) * 64 + i];
      float xv1 = xt[(cb + 1) * 64 + i];
      float xv2 = xt[(cb + 2) * 64 + i];
      float xv3 = xt[(cb + 3) * 64 + i];
#pragma unroll
      for (int r = 0; r < 6; ++r) {
        float4 w = *(const float4*)(rowp[r] + cb);
        acc[r] += xv0 * w.x + xv1 * w.y + xv2 * w.z + xv3 * w.w;
      }
    }
#pragma unroll
    for (int r = 0; r < 6; ++r) {
      int ch24 = g + r * 4;
      int comp = ch24 >> 3, d = ch24 & 7;
      float* dst = (comp == 0) ? qs : (comp == 1) ? ks : vs;
      dst[d * 64 + i] = acc[r];
    }
    __syncthreads();
    float qv[8];
#pragma unroll
    for (int d = 0; d < 8; ++d) qv[d] = qs[d * 64 + i];
    const float* rb = rpbt + h * 4096;
    for (int jj = 0; jj < 16; ++jj) {
      int j = g + jj * 4;
      float s = 0.f;
#pragma unroll
      for (int d = 0; d < 8; ++d) s += qv[d] * ks[d * 64 + j];
      P[j * 64 + i] = s * ATT_SCALE + rb[j * 64 + i];
    }
    __syncthreads();
    if (tid < 64) {
      float m = -1e30f;
      for (int j = 0; j < 64; ++j) m = fmaxf(m, P[j * 64 + tid]);
      float sum = 0.f;
      for (int j = 0; j < 64; ++j) { float p = __expf(P[j * 64 + tid] - m); P[j * 64 + tid] = p; sum += p; }
      invr[tid] = 1.f / sum;
    }
    __syncthreads();
    {
      float s0 = 0.f, s1 = 0.f;
      for (int j = 0; j < 64; ++j) {
        float p = P[j * 64 + i];
        s0 += p * vs[g * 64 + j];
        s1 += p * vs[(g + 4) * 64 + j];
      }
      float inv = invr[i];
      int row = y0 + (i >> 3), col = x0 + (i & 7);
      o_out[((size_t)(b * 64 + h * 8 + g) * 128 + row) * 128 + col] = s0 * inv;
      o_out[((size_t)(b * 64 + h * 8 + g + 4) * 128 + row) * 128 + col] = s1 * inv;
    }
    __syncthreads();
  }
}

// ------- directional avg pools (reflect+zero pad semantics) + add local -------
__global__ __launch_bounds__(256)
void avgadd_k(const float* __restrict__ o, const float* __restrict__ loc, float* __restrict__ out)
{
  int idx = blockIdx.x * 256 + threadIdx.x;
  if (idx >= 8388608) return;
  int x = idx & 127, y = (idx >> 7) & 127;
  size_t p = (size_t)(idx >> 14);
  const float* op = o + (p << 14);
  float s1 = 0.f, s2 = 0.f;
#pragma unroll
  for (int t = 0; t < 8; ++t) {
    int r = y - 3 + t;
    if (r >= 0 && r <= 128) { int rr = (r == 128) ? 126 : r; s1 += op[rr * 128 + x]; }
    int cc = x - 3 + t;
    if (cc >= 0 && cc <= 128) { int ss = (cc == 128) ? 126 : cc; s2 += op[y * 128 + ss]; }
  }
  out[idx] = 0.125f * (s1 + s2) + loc[idx];
}

// ---------------- depthwise 8x8 conv (pad_out + pad3, zero) + BN ----------------
__global__ __launch_bounds__(256)
void dw_k(const float* __restrict__ in, const float* __restrict__ w,
          const float* __restrict__ g, const float* __restrict__ bb, float* __restrict__ out)
{
  __shared__ float t[23 * 23];
  const int tid = threadIdx.x;
  const int tx = tid & 15, ty = tid >> 4;
  const int x0 = blockIdx.x * 16, y0 = blockIdx.y * 16;
  const int pc = blockIdx.z;
  const int c = pc & 63;
  const float* ip = in + (size_t)pc * 16384;
  for (int e = tid; e < 529; e += 256) {
    int yy = e / 23, xx = e % 23;
    int iy = y0 + yy - 3, ix = x0 + xx - 3;
    t[e] = (iy >= 0 && iy < 128 && ix >= 0 && ix < 128) ? ip[iy * 128 + ix] : 0.f;
  }
  __syncthreads();
  const float* wk = w + c * 64;
  float s = 0.f;
#pragma unroll
  for (int ky = 0; ky < 8; ++ky)
#pragma unroll
    for (int kx = 0; kx < 8; ++kx)
      s += t[(ty + ky) * 23 + tx + kx] * wk[ky * 8 + kx];
  out[(size_t)pc * 16384 + (y0 + ty) * 128 + x0 + tx] = s * (g[c] * BN_SC) + bb[c];
}

// ---------------- final 1x1 conv (w_pw, no bias) ----------------
__global__ __launch_bounds__(256)
void pw_k(const float* __restrict__ in, const float* __restrict__ w, float* __restrict__ out)
{
  int idx = blockIdx.x * 256 + threadIdx.x;
  int b = idx >> 14, px = idx & 16383;
  const float* ip = in + ((size_t)b << 20) + px;
  float v[64];
#pragma unroll
  for (int i = 0; i < 64; ++i) v[i] = ip[(size_t)i << 14];
  float* op = out + ((size_t)b << 20) + px;
  for (int co = 0; co < 64; ++co) {
    const float* wk = w + co * 64;
    float s = 0.f;
#pragma unroll
    for (int i = 0; i < 64; ++i) s += v[i] * wk[i];
    op[(size_t)co << 14] = s;
  }
}

// =======================================================================
extern "C" void kernel_launch(void* const* d_in, const int* in_sizes, int n_in,
                              void* d_out, int out_size, void* d_ws, size_t ws_size,
                              hipStream_t stream)
{
  const float* x      = (const float*)d_in[0];
  const float* w_qkv  = (const float*)d_in[1];
  const float* w_l1   = (const float*)d_in[2];
  const float* g_l1   = (const float*)d_in[3];
  const float* b_l1   = (const float*)d_in[4];
  const float* w_l2   = (const float*)d_in[5];
  const float* g_l2   = (const float*)d_in[6];
  const float* b_l2   = (const float*)d_in[7];
  const float* f_cos  = (const float*)d_in[8];
  const float* f_sin  = (const float*)d_in[9];
  const float* gb_b1  = (const float*)d_in[10];
  const float* gb_b2  = (const float*)d_in[11];
  const float* gb_w   = (const float*)d_in[12];
  const float* w_post = (const float*)d_in[13];
  const float* g_post = (const float*)d_in[14];
  const float* b_post = (const float*)d_in[15];
  const float* w_gc   = (const float*)d_in[16];
  const float* b_gc   = (const float*)d_in[17];
  const float* w_gc1  = (const float*)d_in[18];
  const float* b_gc1  = (const float*)d_in[19];
  const float* w_gc2  = (const float*)d_in[20];
  const float* b_gc2  = (const float*)d_in[21];
  const float* rpb    = (const float*)d_in[22];
  const float* w_dw   = (const float*)d_in[23];
  const float* g_proj = (const float*)d_in[24];
  const float* b_proj = (const float*)d_in[25];
  const float* w_pw   = (const float*)d_in[26];
  const int*   relidx = (const int*)d_in[27];
  float* out = (float*)d_out;

  // Workspace: max byte used = 102,238,208 (round-2-proven footprint).
  char* ws = (char*)d_ws;
  float* R1   = (float*)(ws + 0);                       // 32 MiB
  float* R2   = (float*)(ws + 33554432);                // 32 MiB
  float* R3   = (float*)(ws + 67108864);                // convgc out / out0
  float* C1   = R3;                                     // 16,515,072 B complex (FFT)
  float* C2   = (float*)(ws + 83623936);                // 16,515,072 B (ends 100,139,008)
  float* XC5  = (float*)(ws + 100139008);               // 1,968,128 B (steps 8-9)
  float* RPBT = (float*)(ws + 102107136);               // 131,072 B (ends 102,238,208)
  float* W1S  = (float*)(ws + 67108864);                // prep weights (dead before FFT)
  float* W2S  = (float*)(ws + 67108864 + 147456);
  float* BLS  = (float*)(ws + 67108864 + 163840);

  // 1. fold BN into local-branch weights + rpb gather
  prep_k<<<144, 256, 0, stream>>>(w_l1, g_l1, b_l1, w_l2, g_l2, b_l2, W1S, W2S, BLS);
  rpbprep_k<<<128, 256, 0, stream>>>(rpb, relidx, RPBT);
  // 2. local_pre = bn(conv1x1) + bn(conv3x3)  -> R1
  conv3x3r_k<M_LOCAL, 128, 128, 1><<<dim3(32, 8, 4), 256, 0, stream>>>(x, W1S, W2S, BLS, nullptr, R1);
  // 3. gabor conv (valid, cos||sin + biases)  -> R2 (xc0, 126x126)
  conv3x3r_k<M_GABOR, 128, 126, 0><<<dim3(32, 8, 4), 256, 0, stream>>>(R1, f_cos, f_sin, gb_b1, gb_b2, R2);
  // 4. fft_h + fw-mix, 2 chunks of 256 planes -> R1 (xc1)
  for (int chunk = 0; chunk < 2; ++chunk) {
    int pb = chunk * 256;
    dft_rows_fwd_k<<<256 * 126, 64, 0, stream>>>(R2, C1, pb);
    dft_cols_fwd_mask_k<<<512, 256, 0, stream>>>(C1, C2);
    dft_cols_inv_k<<<512, 256, 0, stream>>>(C2, C1);
    dft_rows_inv_mix_k<<<256 * 126, 128, 0, stream>>>(C1, R2, gb_w, R1, pb);
  }
  // 5. relu6(bn(conv3x3 w_post)) -> R2 (xc2)
  conv3x3r_k<M_BNRELU6, 126, 126, 1><<<dim3(32, 8, 4), 256, 0, stream>>>(R1, w_post, nullptr, g_post, b_post, R2);
  // 6. maxpool 2x2 s1 -> R1 (125^2)
  mp1_k<<<31250, 256, 0, stream>>>(R2, R1);
  // 7. relu(conv3x3 s2 w_gc) -> R3 (62^2)   [tiled]
  convgc_t<<<dim3(16, 8, 2), 256, 0, stream>>>(R1, w_gc, b_gc, R3);
  // 8. maxpool 2x2 s2 -> XC5 (31^2)
  mp2_k<<<1922, 256, 0, stream>>>(R3, XC5);
  // 9. bilinear resize 31 -> 128 -> R1 (xc6)
  resize_k<<<32768, 256, 0, stream>>>(XC5, R1);
  // 10. relu(conv3x3 w_gc1 + b) -> R2 (xc7)
  conv3x3r_k<M_BIASRELU, 128, 128, 1><<<dim3(32, 8, 4), 256, 0, stream>>>(R1, w_gc1, nullptr, b_gc1, nullptr, R2);
  // 11. 1x1 conv w_gc2 + log_softmax -> R1 (local)
  pwlsm_k<<<512, 256, 0, stream>>>(R2, w_gc2, b_gc2, R1);
  // 12. window attention -> R2 (o)
  attn_k<<<2048, 256, 0, stream>>>(x, w_qkv, RPBT, R2);
  // 13. ox + oy + local -> R3 (out0)
  avgadd_k<<<32768, 256, 0, stream>>>(R2, R1, R3);
  // 14. depthwise 8x8 + bn -> R2
  dw_k<<<dim3(8, 8, 512), 256, 0, stream>>>(R3, w_dw, g_proj, b_proj, R2);
  // 15. 1x1 conv w_pw -> d_out
  pw_k<<<512, 256, 0, stream>>>(R2, w_pw, out);
  (void)in_sizes; (void)n_in; (void)out_size; (void)ws_size;
}

// Round 9
// 1928.378 us; speedup vs baseline: 2.2268x; 1.0776x over previous
//
#include <hip/hip_runtime.h>
#include <math.h>

#define BN_SC 0.9999950000375f
#define P2N   (6.283185307179586f / 126.f)
#define ATT_SCALE 0.35355339059327373f

typedef float v4f __attribute__((ext_vector_type(4)));

enum { M_LOCAL = 0, M_GABOR = 1, M_BNRELU6 = 2, M_BIASRELU = 3 };

// ---------------- weight prep: fold BN scale into w_l1 / w_l2 ----------------
__global__ __launch_bounds__(256) void prep_k(
    const float* __restrict__ w_l1, const float* __restrict__ g_l1, const float* __restrict__ b_l1,
    const float* __restrict__ w_l2, const float* __restrict__ g_l2, const float* __restrict__ b_l2,
    float* __restrict__ w1s, float* __restrict__ w2s, float* __restrict__ bs)
{
  int i = blockIdx.x * 256 + threadIdx.x;
  if (i < 36864) w1s[i] = w_l1[i] * (g_l1[i / 576] * BN_SC);
  if (i < 4096)  w2s[i] = w_l2[i] * (g_l2[i / 64] * BN_SC);
  if (i < 64)    bs[i]  = b_l1[i] + b_l2[i];
}

// ------------- rpb bias pre-gather: rpbt[h][j*64+i] = rpb[relidx[i*64+j]*8+h] -------------
__global__ __launch_bounds__(256) void rpbprep_k(
    const float* __restrict__ rpb, const int* __restrict__ relidx, float* __restrict__ rpbt)
{
  int idx = blockIdx.x * 256 + threadIdx.x; // 32768
  int h = idx >> 12, r = idx & 4095, j = r >> 6, i = r & 63;
  rpbt[idx] = rpb[relidx[i * 64 + j] * 8 + h];
}

// -------- fp32 register-tiled direct conv3x3 (+fused 1x1 for LOCAL), 64->64 ch --------
template<int MODE, int IN_HW, int OUT_HW, int PAD>
__global__ __launch_bounds__(256)
void conv3x3r_k(const float* __restrict__ in, const float* __restrict__ wa,
                const float* __restrict__ wb, const float* __restrict__ pa,
                const float* __restrict__ pb, float* __restrict__ out)
{
  __shared__ float wsm[64 * 9 * 16];        // [cin][tap][co16]
  __shared__ float w11[64 * 16];            // [cin][co16] (LOCAL 1x1)
  __shared__ float tile[4 * 18 * 37];       // 4 cin x 18 rows x pitch 37
  const int tid = threadIdx.x;
  const int tx = tid & 7, ty = (tid >> 3) & 7, tc = tid >> 6;
  const int bx = blockIdx.x & 3, by = blockIdx.x >> 2;
  const int b = blockIdx.y, cg = blockIdx.z;
  const int x0 = bx * 32, y0 = by * 16;
  const int ix0 = x0 - PAD, iy0 = y0 - PAD;
  const float* inb = in + (size_t)b * 64 * IN_HW * IN_HW;

  for (int e = tid; e < 9216; e += 256) {
    int co = e & 15, q = e >> 4;
    int o = q % 9, cin = q / 9;
    int c = cg * 16 + co;
    float v;
    if (MODE == M_GABOR)
      v = (c < 32) ? wa[((size_t)c * 64 + cin) * 9 + o]
                   : wb[((size_t)(c - 32) * 64 + cin) * 9 + o];
    else
      v = wa[((size_t)c * 64 + cin) * 9 + o];
    wsm[(cin * 9 + o) * 16 + co] = v;
  }
  if (MODE == M_LOCAL) {
    for (int e = tid; e < 1024; e += 256) {
      int co = e & 15, cin = e >> 4;
      w11[cin * 16 + co] = wb[(size_t)(cg * 16 + co) * 64 + cin];
    }
  }

  float acc[4][2][4];
#pragma unroll
  for (int a = 0; a < 4; ++a)
#pragma unroll
    for (int py = 0; py < 2; ++py)
#pragma unroll
      for (int px = 0; px < 4; ++px) acc[a][py][px] = 0.f;

  const int yb = ty * 2, xb = tx * 4;

  for (int cc = 0; cc < 64; cc += 4) {
    __syncthreads();
    for (int e = tid; e < 4 * 18 * 34; e += 256) {
      int ci = e / 612, r = e - ci * 612;
      int row = r / 34, col = r - row * 34;
      int iy = iy0 + row, ix = ix0 + col;
      float v = 0.f;
      if ((unsigned)iy < (unsigned)IN_HW && (unsigned)ix < (unsigned)IN_HW)
        v = inb[((size_t)(cc + ci) * IN_HW + iy) * IN_HW + ix];
      tile[ci * 666 + row * 37 + col] = v;
    }
    __syncthreads();
#pragma unroll
    for (int ci = 0; ci < 4; ++ci) {
      float p[4][6];
#pragma unroll
      for (int r = 0; r < 4; ++r)
#pragma unroll
        for (int c2 = 0; c2 < 6; ++c2)
          p[r][c2] = tile[ci * 666 + (yb + r) * 37 + xb + c2];
      const int cin = cc + ci;
      v4f wv[9];
#pragma unroll
      for (int o = 0; o < 9; ++o)
        wv[o] = *(const v4f*)&wsm[(cin * 9 + o) * 16 + tc * 4];
#pragma unroll
      for (int dy = 0; dy < 3; ++dy)
#pragma unroll
        for (int dx = 0; dx < 3; ++dx) {
          v4f w = wv[dy * 3 + dx];
#pragma unroll
          for (int a = 0; a < 4; ++a) {
            float wc = w[a];
#pragma unroll
            for (int py = 0; py < 2; ++py)
#pragma unroll
              for (int px = 0; px < 4; ++px)
                acc[a][py][px] += p[py + dy][px + dx] * wc;
          }
        }
      if (MODE == M_LOCAL) {
        v4f w1 = *(const v4f*)&w11[cin * 16 + tc * 4];
#pragma unroll
        for (int a = 0; a < 4; ++a) {
          float wc = w1[a];
#pragma unroll
          for (int py = 0; py < 2; ++py)
#pragma unroll
            for (int px = 0; px < 4; ++px)
              acc[a][py][px] += p[py + 1][px + 1] * wc;
        }
      }
    }
  }

#pragma unroll
  for (int a = 0; a < 4; ++a) {
    const int c = cg * 16 + tc * 4 + a;
    float scale = 1.f, bias;
    if (MODE == M_LOCAL)        { bias = pa[c]; }
    else if (MODE == M_GABOR)   { bias = (c < 32) ? pa[c] : pb[c - 32]; }
    else if (MODE == M_BNRELU6) { scale = pa[c] * BN_SC; bias = pb[c]; }
    else                        { bias = pa[c]; }
#pragma unroll
    for (int py = 0; py < 2; ++py) {
      int oy = y0 + yb + py;
      if (oy >= OUT_HW) continue;
      float* op = out + (((size_t)b * 64 + c) * OUT_HW + oy) * OUT_HW;
      int ox0 = x0 + xb;
#pragma unroll
      for (int px = 0; px < 4; ++px) {
        if (ox0 + px >= OUT_HW) continue;
        float r = acc[a][py][px] * scale + bias;
        if (MODE == M_BNRELU6) r = fminf(fmaxf(r, 0.f), 6.f);
        if (MODE == M_BIASRELU) r = fmaxf(r, 0.f);
        op[ox0 + px] = r;
      }
    }
  }
}

// -------- fp32 register-tiled stride-2 conv3x3 valid (125 -> 62), + bias + relu --------
__global__ __launch_bounds__(256)
void convgc_t(const float* __restrict__ in, const float* __restrict__ w,
              const float* __restrict__ bias, float* __restrict__ out)
{
  __shared__ float tile[4 * 33 * 35];
  __shared__ float wt[4 * 9 * 32];
  const int tid = threadIdx.x;
  const int tx = tid & 7, ty = (tid >> 3) & 7, tc = tid >> 6;
  const int bx = blockIdx.x & 3, by = blockIdx.x >> 2;
  const int b = blockIdx.y, zg = blockIdx.z;
  const int x0 = bx * 16, y0 = by * 16;
  const float* inb = in + (size_t)b * 64 * 125 * 125;

  float acc[8][2][2];
#pragma unroll
  for (int a = 0; a < 8; ++a)
#pragma unroll
    for (int py = 0; py < 2; ++py)
#pragma unroll
      for (int px = 0; px < 2; ++px) acc[a][py][px] = 0.f;

  for (int cc = 0; cc < 64; cc += 4) {
    __syncthreads();
    for (int e = tid; e < 4 * 33 * 33; e += 256) {
      int ci = e / 1089, r = e - ci * 1089;
      int row = r / 33, col = r - row * 33;
      int iy = 2 * y0 + row, ix = 2 * x0 + col;
      float v = 0.f;
      if (iy < 125 && ix < 125)
        v = inb[((size_t)(cc + ci) * 125 + iy) * 125 + ix];
      tile[ci * 1155 + row * 35 + col] = v;
    }
    for (int e = tid; e < 1152; e += 256) {
      int co = e & 31, q = e >> 5;
      int ci = q / 9, o = q - ci * 9;
      wt[q * 32 + co] = w[((size_t)(zg * 32 + co) * 64 + cc + ci) * 9 + o];
    }
    __syncthreads();
#pragma unroll
    for (int ci = 0; ci < 4; ++ci) {
      float p[5][5];
#pragma unroll
      for (int r = 0; r < 5; ++r)
#pragma unroll
        for (int c2 = 0; c2 < 5; ++c2)
          p[r][c2] = tile[ci * 1155 + (4 * ty + r) * 35 + 4 * tx + c2];
#pragma unroll
      for (int o = 0; o < 9; ++o) {
        const int dy = o / 3, dx = o - dy * 3;
        v4f w0 = *(const v4f*)&wt[(ci * 9 + o) * 32 + tc * 8];
        v4f w1 = *(const v4f*)&wt[(ci * 9 + o) * 32 + tc * 8 + 4];
#pragma unroll
        for (int py = 0; py < 2; ++py)
#pragma unroll
          for (int px = 0; px < 2; ++px) {
            float pv = p[2 * py + dy][2 * px + dx];
#pragma unroll
            for (int a = 0; a < 4; ++a) {
              acc[a][py][px]     += pv * w0[a];
              acc[a + 4][py][px] += pv * w1[a];
            }
          }
      }
    }
  }

#pragma unroll
  for (int a = 0; a < 8; ++a) {
    const int c = zg * 32 + tc * 8 + a;
    const float bv = bias[c];
#pragma unroll
    for (int py = 0; py < 2; ++py) {
      int oy = y0 + ty * 2 + py;
      if (oy >= 62) continue;
      float* op = out + (((size_t)b * 64 + c) * 62 + oy) * 62;
#pragma unroll
      for (int px = 0; px < 2; ++px) {
        int ox = x0 + tx * 2 + px;
        if (ox >= 62) continue;
        op[ox] = fmaxf(acc[a][py][px] + bv, 0.f);
      }
    }
  }
}

// ======================= DFT (126-pt), table-based, Hermitian-half =======================

__global__ __launch_bounds__(64)
void dft_rows_fwd_k(const float* __restrict__ in, float* __restrict__ outC, int planeBase)
{
  __shared__ float2 r2[63];
  __shared__ float2 T[126];
  const int lp = blockIdx.x / 126, n1 = blockIdx.x % 126;
  const int tid = threadIdx.x;
  const float2* row = (const float2*)(in + (size_t)(planeBase + lp) * 15876 + (size_t)n1 * 126);
  if (tid < 63) r2[tid] = row[tid];
  for (int e = tid; e < 126; e += 64) { float s, c; sincosf(P2N * (float)e, &s, &c); T[e] = make_float2(c, s); }
  __syncthreads();
  const int k2 = tid;
  const int inc = (2 * k2) % 126;
  int m = 0;
  float Er = 0.f, Ei = 0.f, Or = 0.f, Oi = 0.f;
  for (int n = 0; n < 63; ++n) {
    float2 rv = r2[n];
    float2 t = T[m];
    Er += rv.x * t.x; Ei -= rv.x * t.y;
    Or += rv.y * t.x; Oi -= rv.y * t.y;
    m += inc; if (m >= 126) m -= 126;
  }
  float c = T[k2].x, s = T[k2].y;
  float2* o = (float2*)(outC + (size_t)lp * 16128 + (size_t)n1 * 128);
  o[k2] = make_float2(Er + c * Or + s * Oi, Ei + c * Oi - s * Or);
}

__global__ __launch_bounds__(256)
void dft_cols_fwd_mask_k(const float* __restrict__ inC, float* __restrict__ outC)
{
  __shared__ float2 S[4032];
  __shared__ float2 T[126];
  const int lp = blockIdx.x >> 1, gbase = (blockIdx.x & 1) * 32;
  const int tid = threadIdx.x;
  if (tid < 126) { float s, c; sincosf(P2N * (float)tid, &s, &c); T[tid] = make_float2(c, s); }
  const float2* src = (const float2*)(inC + (size_t)lp * 16128);
  for (int e = tid; e < 4032; e += 256) {
    int n1 = e >> 5, c = e & 31;
    S[e] = src[n1 * 64 + gbase + c];
  }
  __syncthreads();
  float2* dst = (float2*)(outC + (size_t)lp * 16128);
  for (int e = tid; e < 2016; e += 256) {
    int k1 = e >> 5, c = e & 31;
    int k2 = gbase + c;
    int inc = 2 * k1;
    int me = 0, mo = k1;
    float Er = 0.f, Ei = 0.f, Or = 0.f, Oi = 0.f;
    for (int u = 0; u < 63; ++u) {
      float2 s0 = S[(2 * u) * 32 + c];
      float2 t0 = T[me];
      Er += s0.x * t0.x + s0.y * t0.y;
      Ei += s0.y * t0.x - s0.x * t0.y;
      float2 s1 = S[(2 * u + 1) * 32 + c];
      float2 t1 = T[mo];
      Or += s1.x * t1.x + s1.y * t1.y;
      Oi += s1.y * t1.x - s1.x * t1.y;
      me += inc; if (me >= 126) me -= 126;
      mo += inc; if (mo >= 126) mo -= 126;
    }
    int f2 = (k2 <= 62) ? k2 : k2 - 126;
    float ar = Er + Or, ai = Ei + Oi;
    float br = Er - Or, bi = Ei - Oi;
    float sa = (k1 * k1 + f2 * f2 > 1600) ? sqrtf(ar * ar + ai * ai) * (1.f / 15876.f) : 0.f;
    int f1b = k1 - 63;
    float sb = (f1b * f1b + f2 * f2 > 1600) ? sqrtf(br * br + bi * bi) * (1.f / 15876.f) : 0.f;
    dst[(size_t)k1 * 64 + k2]        = make_float2(ar * sa, ai * sa);
    dst[(size_t)(k1 + 63) * 64 + k2] = make_float2(br * sb, bi * sb);
  }
}

__global__ __launch_bounds__(256)
void dft_cols_inv_k(const float* __restrict__ inC, float* __restrict__ outC)
{
  __shared__ float2 S[4032];
  __shared__ float2 T[126];
  const int lp = blockIdx.x >> 1, gbase = (blockIdx.x & 1) * 32;
  const int tid = threadIdx.x;
  if (tid < 126) { float s, c; sincosf(P2N * (float)tid, &s, &c); T[tid] = make_float2(c, s); }
  const float2* src = (const float2*)(inC + (size_t)lp * 16128);
  for (int e = tid; e < 4032; e += 256) {
    int k1 = e >> 5, c = e & 31;
    S[e] = src[k1 * 64 + gbase + c];
  }
  __syncthreads();
  float2* dst = (float2*)(outC + (size_t)lp * 16128);
  for (int e = tid; e < 2016; e += 256) {
    int n1 = e >> 5, c = e & 31;
    int k2 = gbase + c;
    int inc = (2 * n1) % 126;
    int me = 0, mo = n1;
    float Er = 0.f, Ei = 0.f, Or = 0.f, Oi = 0.f;
    for (int u = 0; u < 63; ++u) {
      float2 s0 = S[(2 * u) * 32 + c];
      float2 t0 = T[me];
      Er += s0.x * t0.x - s0.y * t0.y;
      Ei += s0.x * t0.y + s0.y * t0.x;
      float2 s1 = S[(2 * u + 1) * 32 + c];
      float2 t1 = T[mo];
      Or += s1.x * t1.x - s1.y * t1.y;
      Oi += s1.x * t1.y + s1.y * t1.x;
      me += inc; if (me >= 126) me -= 126;
      mo += inc; if (mo >= 126) mo -= 126;
    }
    dst[(size_t)n1 * 64 + k2]        = make_float2(Er + Or, Ei + Oi);
    dst[(size_t)(n1 + 63) * 64 + k2] = make_float2(Er - Or, Ei - Oi);
  }
}

__global__ __launch_bounds__(128)
void dft_rows_inv_mix_k(const float* __restrict__ inC, const float* __restrict__ xc0,
                        const float* __restrict__ gb_w, float* __restrict__ out, int planeBase)
{
  __shared__ float2 Z[64];
  __shared__ float2 T[126];
  const int lp = blockIdx.x / 126, n1 = blockIdx.x % 126;
  const int tid = threadIdx.x;
  const float2* src = (const float2*)(inC + (size_t)lp * 16128 + (size_t)n1 * 128);
  if (tid < 64) Z[tid] = src[tid];
  if (tid < 126) { float s, c; sincosf(P2N * (float)tid, &s, &c); T[tid] = make_float2(c, s); }
  __syncthreads();
  const int n2 = tid;
  if (n2 < 126) {
    float a = Z[0].x + ((n2 & 1) ? -Z[63].x : Z[63].x);
    float acc = 0.f;
    int m = n2;
    for (int k2 = 1; k2 < 63; ++k2) {
      float2 z = Z[k2];
      float2 t = T[m];
      acc += z.x * t.x - z.y * t.y;
      m += n2; if (m >= 126) m -= 126;
    }
    a += 2.f * acc;
    float w0 = fmaxf(gb_w[0], 0.f), w1 = fmaxf(gb_w[1], 0.f);
    float inv = 1.f / (w0 + w1 + 1e-8f);
    size_t gi = (size_t)(planeBase + lp) * 15876 + (size_t)n1 * 126 + n2;
    out[gi] = (w0 * inv) * fabsf(a) + (w1 * inv) * xc0[gi];
  }
}

// ---------------- maxpool 2x2 stride1: 126 -> 125 ----------------
__global__ __launch_bounds__(256) void mp1_k(const float* __restrict__ in, float* __restrict__ out)
{
  int idx = blockIdx.x * 256 + threadIdx.x;
  if (idx >= 512 * 125 * 125) return;
  int x = idx % 125, y = (idx / 125) % 125, p = idx / 15625;
  const float* ip = in + (size_t)p * 15876 + (size_t)y * 126 + x;
  out[idx] = fmaxf(fmaxf(ip[0], ip[1]), fmaxf(ip[126], ip[127]));
}

// ---------------- maxpool 2x2 stride2: 62 -> 31 ----------------
__global__ __launch_bounds__(256) void mp2_k(const float* __restrict__ in, float* __restrict__ out)
{
  int idx = blockIdx.x * 256 + threadIdx.x;
  if (idx >= 512 * 31 * 31) return;
  int x = idx % 31, y = (idx / 31) % 31, p = idx / 961;
  const float* ip = in + (size_t)p * 3844 + (size_t)(2 * y) * 62 + 2 * x;
  out[idx] = fmaxf(fmaxf(ip[0], ip[1]), fmaxf(ip[62], ip[63]));
}

// ---------------- bilinear resize 31 -> 128 ----------------
__global__ __launch_bounds__(256) void resize_k(const float* __restrict__ in, float* __restrict__ out)
{
  int idx = blockIdx.x * 256 + threadIdx.x;
  if (idx >= 512 * 128 * 128) return;
  int x = idx & 127, y = (idx >> 7) & 127, p = idx >> 14;
  float sy = (y + 0.5f) * (31.f / 128.f) - 0.5f; sy = fminf(fmaxf(sy, 0.f), 30.f);
  float sx = (x + 0.5f) * (31.f / 128.f) - 0.5f; sx = fminf(fmaxf(sx, 0.f), 30.f);
  int y0 = (int)sy; float fy = sy - (float)y0; int y1 = min(y0 + 1, 30);
  int x0 = (int)sx; float fx = sx - (float)x0; int x1 = min(x0 + 1, 30);
  const float* ip = in + (size_t)p * 961;
  float v = (1.f - fy) * ((1.f - fx) * ip[y0 * 31 + x0] + fx * ip[y0 * 31 + x1])
          + fy         * ((1.f - fx) * ip[y1 * 31 + x0] + fx * ip[y1 * 31 + x1]);
  out[idx] = v;
}

// ---------------- 1x1 conv (w_gc2 + bias) + log_softmax over 64 channels ----------------
__global__ __launch_bounds__(256)
void pwlsm_k(const float* __restrict__ in, const float* __restrict__ w,
             const float* __restrict__ bias, float* __restrict__ out)
{
  __shared__ float zs[64 * 256];
  int idx = blockIdx.x * 256 + threadIdx.x;
  int b = idx >> 14, px = idx & 16383;
  const float* ip = in + ((size_t)b << 20) + px;
  float v[64];
#pragma unroll
  for (int i = 0; i < 64; ++i) v[i] = ip[(size_t)i << 14];
  float m = -1e30f;
  for (int co = 0; co < 64; ++co) {
    float s = bias[co];
    const float* wk = w + co * 64;
#pragma unroll
    for (int i = 0; i < 64; ++i) s += v[i] * wk[i];
    zs[co * 256 + threadIdx.x] = s;
    m = fmaxf(m, s);
  }
  float sum = 0.f;
  for (int co = 0; co < 64; ++co) sum += __expf(zs[co * 256 + threadIdx.x] - m);
  float lse = m + __logf(sum);
  float* op = out + ((size_t)b << 20) + px;
  for (int co = 0; co < 64; ++co) op[(size_t)co << 14] = zs[co * 256 + threadIdx.x] - lse;
}

// ---------------- windowed attention: wave-per-head, register softmax ----------------
// 4 waves/block; wave wv handles heads wv and wv+4. Private k/v LDS per wave laid out
// [j][d] (pitch 8) so dot/PV reads are wave-broadcast float4s. q and the 64-entry score
// row P stay in registers per lane -> softmax is register-local, no block-wide stalls.
__global__ __launch_bounds__(256)
void attn_w_k(const float* __restrict__ x, const float* __restrict__ wqkv,
              const float* __restrict__ rpbt, float* __restrict__ o_out)
{
  __shared__ float xt[4096];            // [cin][pix] 16 KB
  __shared__ float kvb[4][2][64][8];    // [wave][k|v][j][d] 16 KB
  const int tid = threadIdx.x;
  const int lane = tid & 63;
  const int wv = __builtin_amdgcn_readfirstlane(tid >> 6);
  const int b = blockIdx.x >> 8, gy = (blockIdx.x >> 4) & 15, gx = blockIdx.x & 15;
  const int y0 = gy * 8, x0 = gx * 8;

  for (int e = tid; e < 4096; e += 256) {
    int cin = e >> 6, pix = e & 63;
    xt[e] = x[((size_t)(b * 64 + cin) * 128 + (y0 + (pix >> 3))) * 128 + x0 + (pix & 7)];
  }
  __syncthreads();

  const int row = y0 + (lane >> 3), col = x0 + (lane & 7);

  for (int hh = 0; hh < 2; ++hh) {
    const int h = hh * 4 + wv;      // wave-uniform
    // ---- qkv for pixel i=lane, head h (weights via wave-uniform scalar loads) ----
    const float* wq = wqkv + (size_t)(h * 8) * 64;
    const float* wk = wqkv + (size_t)(64 + h * 8) * 64;
    const float* wvv = wqkv + (size_t)(128 + h * 8) * 64;
    float q[8], kk[8], vv[8];
#pragma unroll
    for (int d = 0; d < 8; ++d) { q[d] = 0.f; kk[d] = 0.f; vv[d] = 0.f; }
    for (int cb = 0; cb < 64; cb += 4) {
      float xv0 = xt[(cb + 0) * 64 + lane];
      float xv1 = xt[(cb + 1) * 64 + lane];
      float xv2 = xt[(cb + 2) * 64 + lane];
      float xv3 = xt[(cb + 3) * 64 + lane];
#pragma unroll
      for (int d = 0; d < 8; ++d) {
        float4 a = *(const float4*)(wq + d * 64 + cb);
        q[d] += xv0 * a.x + xv1 * a.y + xv2 * a.z + xv3 * a.w;
        float4 bq = *(const float4*)(wk + d * 64 + cb);
        kk[d] += xv0 * bq.x + xv1 * bq.y + xv2 * bq.z + xv3 * bq.w;
        float4 cq = *(const float4*)(wvv + d * 64 + cb);
        vv[d] += xv0 * cq.x + xv1 * cq.y + xv2 * cq.z + xv3 * cq.w;
      }
    }
#pragma unroll
    for (int d = 0; d < 8; ++d) {
      kvb[wv][0][lane][d] = kk[d];
      kvb[wv][1][lane][d] = vv[d];
    }
    __syncthreads();

    // ---- dots + bias + register softmax ----
    const float* rb = rpbt + h * 4096;
    float P[64];
    float m = -1e30f;
#pragma unroll
    for (int j = 0; j < 64; ++j) {
      float4 k0 = *(const float4*)&kvb[wv][0][j][0];
      float4 k1 = *(const float4*)&kvb[wv][0][j][4];
      float s = q[0] * k0.x + q[1] * k0.y + q[2] * k0.z + q[3] * k0.w
              + q[4] * k1.x + q[5] * k1.y + q[6] * k1.z + q[7] * k1.w;
      s = s * ATT_SCALE + rb[j * 64 + lane];
      P[j] = s;
      m = fmaxf(m, s);
    }
    float sum = 0.f;
#pragma unroll
    for (int j = 0; j < 64; ++j) { float p = __expf(P[j] - m); P[j] = p; sum += p; }
    float inv = 1.f / sum;

    // ---- PV ----
    float acc[8];
#pragma unroll
    for (int d = 0; d < 8; ++d) acc[d] = 0.f;
#pragma unroll
    for (int j = 0; j < 64; ++j) {
      float p = P[j];
      float4 v0 = *(const float4*)&kvb[wv][1][j][0];
      float4 v1 = *(const float4*)&kvb[wv][1][j][4];
      acc[0] += p * v0.x; acc[1] += p * v0.y; acc[2] += p * v0.z; acc[3] += p * v0.w;
      acc[4] += p * v1.x; acc[5] += p * v1.y; acc[6] += p * v1.z; acc[7] += p * v1.w;
    }
#pragma unroll
    for (int d = 0; d < 8; ++d)
      o_out[((size_t)(b * 64 + h * 8 + d) * 128 + row) * 128 + col] = acc[d] * inv;
    __syncthreads();   // protect kvb before next head overwrites
  }
}

// ------- directional avg pools (reflect+zero pad semantics) + add local -------
__global__ __launch_bounds__(256)
void avgadd_k(const float* __restrict__ o, const float* __restrict__ loc, float* __restrict__ out)
{
  int idx = blockIdx.x * 256 + threadIdx.x;
  if (idx >= 8388608) return;
  int x = idx & 127, y = (idx >> 7) & 127;
  size_t p = (size_t)(idx >> 14);
  const float* op = o + (p << 14);
  float s1 = 0.f, s2 = 0.f;
#pragma unroll
  for (int t = 0; t < 8; ++t) {
    int r = y - 3 + t;
    if (r >= 0 && r <= 128) { int rr = (r == 128) ? 126 : r; s1 += op[rr * 128 + x]; }
    int cc = x - 3 + t;
    if (cc >= 0 && cc <= 128) { int ss = (cc == 128) ? 126 : cc; s2 += op[y * 128 + ss]; }
  }
  out[idx] = 0.125f * (s1 + s2) + loc[idx];
}

// ---------------- depthwise 8x8 conv (pad_out + pad3, zero) + BN ----------------
__global__ __launch_bounds__(256)
void dw_k(const float* __restrict__ in, const float* __restrict__ w,
          const float* __restrict__ g, const float* __restrict__ bb, float* __restrict__ out)
{
  __shared__ float t[23 * 23];
  const int tid = threadIdx.x;
  const int tx = tid & 15, ty = tid >> 4;
  const int x0 = blockIdx.x * 16, y0 = blockIdx.y * 16;
  const int pc = blockIdx.z;
  const int c = pc & 63;
  const float* ip = in + (size_t)pc * 16384;
  for (int e = tid; e < 529; e += 256) {
    int yy = e / 23, xx = e % 23;
    int iy = y0 + yy - 3, ix = x0 + xx - 3;
    t[e] = (iy >= 0 && iy < 128 && ix >= 0 && ix < 128) ? ip[iy * 128 + ix] : 0.f;
  }
  __syncthreads();
  const float* wk = w + c * 64;
  float s = 0.f;
#pragma unroll
  for (int ky = 0; ky < 8; ++ky)
#pragma unroll
    for (int kx = 0; kx < 8; ++kx)
      s += t[(ty + ky) * 23 + tx + kx] * wk[ky * 8 + kx];
  out[(size_t)pc * 16384 + (y0 + ty) * 128 + x0 + tx] = s * (g[c] * BN_SC) + bb[c];
}

// ---------------- final 1x1 conv (w_pw, no bias) ----------------
__global__ __launch_bounds__(256)
void pw_k(const float* __restrict__ in, const float* __restrict__ w, float* __restrict__ out)
{
  int idx = blockIdx.x * 256 + threadIdx.x;
  int b = idx >> 14, px = idx & 16383;
  const float* ip = in + ((size_t)b << 20) + px;
  float v[64];
#pragma unroll
  for (int i = 0; i < 64; ++i) v[i] = ip[(size_t)i << 14];
  float* op = out + ((size_t)b << 20) + px;
  for (int co = 0; co < 64; ++co) {
    const float* wk = w + co * 64;
    float s = 0.f;
#pragma unroll
    for (int i = 0; i < 64; ++i) s += v[i] * wk[i];
    op[(size_t)co << 14] = s;
  }
}

// =======================================================================
extern "C" void kernel_launch(void* const* d_in, const int* in_sizes, int n_in,
                              void* d_out, int out_size, void* d_ws, size_t ws_size,
                              hipStream_t stream)
{
  const float* x      = (const float*)d_in[0];
  const float* w_qkv  = (const float*)d_in[1];
  const float* w_l1   = (const float*)d_in[2];
  const float* g_l1   = (const float*)d_in[3];
  const float* b_l1   = (const float*)d_in[4];
  const float* w_l2   = (const float*)d_in[5];
  const float* g_l2   = (const float*)d_in[6];
  const float* b_l2   = (const float*)d_in[7];
  const float* f_cos  = (const float*)d_in[8];
  const float* f_sin  = (const float*)d_in[9];
  const float* gb_b1  = (const float*)d_in[10];
  const float* gb_b2  = (const float*)d_in[11];
  const float* gb_w   = (const float*)d_in[12];
  const float* w_post = (const float*)d_in[13];
  const float* g_post = (const float*)d_in[14];
  const float* b_post = (const float*)d_in[15];
  const float* w_gc   = (const float*)d_in[16];
  const float* b_gc   = (const float*)d_in[17];
  const float* w_gc1  = (const float*)d_in[18];
  const float* b_gc1  = (const float*)d_in[19];
  const float* w_gc2  = (const float*)d_in[20];
  const float* b_gc2  = (const float*)d_in[21];
  const float* rpb    = (const float*)d_in[22];
  const float* w_dw   = (const float*)d_in[23];
  const float* g_proj = (const float*)d_in[24];
  const float* b_proj = (const float*)d_in[25];
  const float* w_pw   = (const float*)d_in[26];
  const int*   relidx = (const int*)d_in[27];
  float* out = (float*)d_out;

  // Workspace: max byte used = 102,238,208 (round-2-proven footprint).
  char* ws = (char*)d_ws;
  float* R1   = (float*)(ws + 0);                       // 32 MiB
  float* R2   = (float*)(ws + 33554432);                // 32 MiB
  float* R3   = (float*)(ws + 67108864);                // convgc out / out0
  float* C1   = R3;                                     // 16,515,072 B complex (FFT)
  float* C2   = (float*)(ws + 83623936);                // 16,515,072 B (ends 100,139,008)
  float* XC5  = (float*)(ws + 100139008);               // 1,968,128 B (steps 8-9)
  float* RPBT = (float*)(ws + 102107136);               // 131,072 B (ends 102,238,208)
  float* W1S  = (float*)(ws + 67108864);                // prep weights (dead before FFT)
  float* W2S  = (float*)(ws + 67108864 + 147456);
  float* BLS  = (float*)(ws + 67108864 + 163840);

  // 1. fold BN into local-branch weights + rpb gather
  prep_k<<<144, 256, 0, stream>>>(w_l1, g_l1, b_l1, w_l2, g_l2, b_l2, W1S, W2S, BLS);
  rpbprep_k<<<128, 256, 0, stream>>>(rpb, relidx, RPBT);
  // 2. local_pre = bn(conv1x1) + bn(conv3x3)  -> R1
  conv3x3r_k<M_LOCAL, 128, 128, 1><<<dim3(32, 8, 4), 256, 0, stream>>>(x, W1S, W2S, BLS, nullptr, R1);
  // 3. gabor conv (valid, cos||sin + biases)  -> R2 (xc0, 126x126)
  conv3x3r_k<M_GABOR, 128, 126, 0><<<dim3(32, 8, 4), 256, 0, stream>>>(R1, f_cos, f_sin, gb_b1, gb_b2, R2);
  // 4. fft_h + fw-mix, 2 chunks of 256 planes -> R1 (xc1)
  for (int chunk = 0; chunk < 2; ++chunk) {
    int pb = chunk * 256;
    dft_rows_fwd_k<<<256 * 126, 64, 0, stream>>>(R2, C1, pb);
    dft_cols_fwd_mask_k<<<512, 256, 0, stream>>>(C1, C2);
    dft_cols_inv_k<<<512, 256, 0, stream>>>(C2, C1);
    dft_rows_inv_mix_k<<<256 * 126, 128, 0, stream>>>(C1, R2, gb_w, R1, pb);
  }
  // 5. relu6(bn(conv3x3 w_post)) -> R2 (xc2)
  conv3x3r_k<M_BNRELU6, 126, 126, 1><<<dim3(32, 8, 4), 256, 0, stream>>>(R1, w_post, nullptr, g_post, b_post, R2);
  // 6. maxpool 2x2 s1 -> R1 (125^2)
  mp1_k<<<31250, 256, 0, stream>>>(R2, R1);
  // 7. relu(conv3x3 s2 w_gc) -> R3 (62^2)   [tiled]
  convgc_t<<<dim3(16, 8, 2), 256, 0, stream>>>(R1, w_gc, b_gc, R3);
  // 8. maxpool 2x2 s2 -> XC5 (31^2)
  mp2_k<<<1922, 256, 0, stream>>>(R3, XC5);
  // 9. bilinear resize 31 -> 128 -> R1 (xc6)
  resize_k<<<32768, 256, 0, stream>>>(XC5, R1);
  // 10. relu(conv3x3 w_gc1 + b) -> R2 (xc7)
  conv3x3r_k<M_BIASRELU, 128, 128, 1><<<dim3(32, 8, 4), 256, 0, stream>>>(R1, w_gc1, nullptr, b_gc1, nullptr, R2);
  // 11. 1x1 conv w_gc2 + log_softmax -> R1 (local)
  pwlsm_k<<<512, 256, 0, stream>>>(R2, w_gc2, b_gc2, R1);
  // 12. window attention -> R2 (o)   [wave-per-head]
  attn_w_k<<<2048, 256, 0, stream>>>(x, w_qkv, RPBT, R2);
  // 13. ox + oy + local -> R3 (out0)
  avgadd_k<<<32768, 256, 0, stream>>>(R2, R1, R3);
  // 14. depthwise 8x8 + bn -> R2
  dw_k<<<dim3(8, 8, 512), 256, 0, stream>>>(R3, w_dw, g_proj, b_proj, R2);
  // 15. 1x1 conv w_pw -> d_out
  pw_k<<<512, 256, 0, stream>>>(R2, w_pw, out);
  (void)in_sizes; (void)n_in; (void)out_size; (void)ws_size;
}